// Round 12
// baseline (175.341 us; speedup 1.0000x reference)
//
#include <hip/hip_runtime.h>

typedef unsigned short u16;
typedef unsigned int u32;
typedef __attribute__((ext_vector_type(8))) short bf16x8_t;
typedef __attribute__((ext_vector_type(4))) float f32x4_t;

// Problem constants: B=4, S=4096, H=1024, N=16, D=64, K-pool=64

#define MFMA_BF16 __builtin_amdgcn_mfma_f32_16x16x32_bf16

__device__ __forceinline__ u16 f2bf(float f) {
  union { float f; u32 u; } a; a.f = f;
  u32 u = a.u;
  u32 r = (u + 0x7FFFu + ((u >> 16) & 1u)) >> 16;  // RNE
  return (u16)r;
}

__device__ __forceinline__ void async_load16(const void* g, void* l) {
  __builtin_amdgcn_global_load_lds(
      (const __attribute__((address_space(1))) void*)g,
      (__attribute__((address_space(3))) void*)l, 16, 0, 0);
}

// stage 64 rows x 128B (8KB, one issue/thread) with chunk pre-swizzle
__device__ __forceinline__ void stage64(const u16* __restrict__ src,
                                        char* lds_base, int t) {
  const int r = t >> 3;
  const int gch = (t & 7) ^ (r & 7);
  async_load16(src + (size_t)r * 1024 + gch * 8, lds_base + (t >> 6) * 1024);
}

__device__ __forceinline__ void acc4(float4& a, const float4 b) {
  a.x += b.x; a.y += b.y; a.z += b.z; a.w += b.w;
}

// cvt 16 fp32 (one row, cols q4*16..+15) -> bf16, ds_write 2 swizzled 16B chunks
__device__ __forceinline__ void cvt_write_row(const float4 a0, const float4 a1,
                                              const float4 a2, const float4 a3,
                                              int row, int q4, char* base) {
  bf16x8_t c0, c1;
  c0[0] = (short)f2bf(a0.x); c0[1] = (short)f2bf(a0.y);
  c0[2] = (short)f2bf(a0.z); c0[3] = (short)f2bf(a0.w);
  c0[4] = (short)f2bf(a1.x); c0[5] = (short)f2bf(a1.y);
  c0[6] = (short)f2bf(a1.z); c0[7] = (short)f2bf(a1.w);
  c1[0] = (short)f2bf(a2.x); c1[1] = (short)f2bf(a2.y);
  c1[2] = (short)f2bf(a2.z); c1[3] = (short)f2bf(a2.w);
  c1[4] = (short)f2bf(a3.x); c1[5] = (short)f2bf(a3.y);
  c1[6] = (short)f2bf(a3.z); c1[7] = (short)f2bf(a3.w);
  const int sw = row & 7;
  *(bf16x8_t*)(base + (size_t)row * 128 + (((2 * q4) ^ sw) << 4)) = c0;
  *(bf16x8_t*)(base + (size_t)row * 128 + (((2 * q4 + 1) ^ sw) << 4)) = c1;
}

// ---------------- fused streaming pre-pass: downsample + 4x transpose ----------------
// z in [0,512): downsample key/value bucket; z in [512,1536): weight transpose tile.
__global__ __launch_bounds__(512) void fused_stream(
    const float* __restrict__ key, const float* __restrict__ value,
    const float* __restrict__ W0, const float* __restrict__ W1,
    const float* __restrict__ W2, const float* __restrict__ W3,
    u16* __restrict__ keyd, u16* __restrict__ valued, u16* __restrict__ T0,
    u16* __restrict__ T1, u16* __restrict__ T2, u16* __restrict__ T3) {
  __shared__ char smem[32768];
  const int z = blockIdx.x;
  const int t = threadIdx.x;
  if (z < 512) {
    float (*part)[256][4] = (float(*)[256][4])smem;  // [8][256][4] = 32KB
    const int bkk = z & 255;
    const float* x = (z >= 256) ? value : key;
    u16* xd = (z >= 256) ? valued : keyd;
    const int lane = t & 63, w = t >> 6;
    const float* base = x + (size_t)bkk * 65536 + (size_t)w * 8 * 1024;
#define LD4(j, s) (*(const float4*)(base + (size_t)(j) * 1024 + ((s) * 64 + lane) * 4))
    float4 a0 = {0.f, 0.f, 0.f, 0.f}, a1 = a0, a2 = a0, a3 = a0;
    float4 u0 = LD4(0, 0), u1 = LD4(0, 1), u2 = LD4(0, 2), u3 = LD4(0, 3);
    float4 u4 = LD4(1, 0), u5 = LD4(1, 1), u6 = LD4(1, 2), u7 = LD4(1, 3);
    float4 v0 = LD4(2, 0), v1 = LD4(2, 1), v2 = LD4(2, 2), v3 = LD4(2, 3);
    float4 v4 = LD4(3, 0), v5 = LD4(3, 1), v6 = LD4(3, 2), v7 = LD4(3, 3);
    acc4(a0, u0); acc4(a1, u1); acc4(a2, u2); acc4(a3, u3);
    acc4(a0, u4); acc4(a1, u5); acc4(a2, u6); acc4(a3, u7);
    u0 = LD4(4, 0); u1 = LD4(4, 1); u2 = LD4(4, 2); u3 = LD4(4, 3);
    u4 = LD4(5, 0); u5 = LD4(5, 1); u6 = LD4(5, 2); u7 = LD4(5, 3);
    acc4(a0, v0); acc4(a1, v1); acc4(a2, v2); acc4(a3, v3);
    acc4(a0, v4); acc4(a1, v5); acc4(a2, v6); acc4(a3, v7);
    v0 = LD4(6, 0); v1 = LD4(6, 1); v2 = LD4(6, 2); v3 = LD4(6, 3);
    v4 = LD4(7, 0); v5 = LD4(7, 1); v6 = LD4(7, 2); v7 = LD4(7, 3);
    acc4(a0, u0); acc4(a1, u1); acc4(a2, u2); acc4(a3, u3);
    acc4(a0, u4); acc4(a1, u5); acc4(a2, u6); acc4(a3, u7);
    acc4(a0, v0); acc4(a1, v1); acc4(a2, v2); acc4(a3, v3);
    acc4(a0, v4); acc4(a1, v5); acc4(a2, v6); acc4(a3, v7);
#undef LD4
    *(float4*)&part[w][0 * 64 + lane][0] = a0;
    *(float4*)&part[w][1 * 64 + lane][0] = a1;
    *(float4*)&part[w][2 * 64 + lane][0] = a2;
    *(float4*)&part[w][3 * 64 + lane][0] = a3;
    __syncthreads();
    if (t < 256) {
      float4 s = {0.f, 0.f, 0.f, 0.f};
#pragma unroll
      for (int w2 = 0; w2 < 8; ++w2) {
        const float4 v = *(const float4*)&part[w2][t][0];
        s.x += v.x; s.y += v.y; s.z += v.z; s.w += v.w;
      }
      ushort4 r;
      r.x = f2bf(s.x * 0.015625f);
      r.y = f2bf(s.y * 0.015625f);
      r.z = f2bf(s.z * 0.015625f);
      r.w = f2bf(s.w * 0.015625f);
      *(ushort4*)(xd + (size_t)bkk * 1024 + t * 4) = r;
    }
  } else {
    float (*tile)[65] = (float(*)[65])smem;  // [64][65]
    const int blk = z - 512;
    const int wsel = blk >> 8, tidx = blk & 255;
    const float* W = (wsel == 0) ? W0 : (wsel == 1) ? W1 : (wsel == 2) ? W2 : W3;
    u16* WT = (wsel == 0) ? T0 : (wsel == 1) ? T1 : (wsel == 2) ? T2 : T3;
    const int tr = (tidx >> 4) * 64;
    const int tc = (tidx & 15) * 64;
#pragma unroll
    for (int i = 0; i < 8; ++i) {
      int idx = i * 512 + t;
      int r = idx >> 6, c = idx & 63;
      tile[r][c] = W[(size_t)(tr + r) * 1024 + tc + c];
    }
    __syncthreads();
#pragma unroll
    for (int i = 0; i < 8; ++i) {
      int idx = i * 512 + t;
      int r = idx >> 6, c = idx & 63;
      WT[(size_t)(tc + r) * 1024 + tr + c] = f2bf(tile[c][r]);
    }
  }
}

// ---------------- fused small GEMMs (M=256): kd and vd^T in one launch ----------------
__global__ __launch_bounds__(256) void gemm_kv(const u16* __restrict__ A0,
                                               const u16* __restrict__ A1,
                                               const u16* __restrict__ BT0,
                                               const u16* __restrict__ BT1,
                                               const float* __restrict__ bias0,
                                               const float* __restrict__ bias1,
                                               u16* __restrict__ C0,
                                               u16* __restrict__ C1) {
  constexpr int K = 1024, BK = 32;
  __shared__ u16 sA[128 * BK];
  __shared__ u16 sB[128 * BK];
  const int z = blockIdx.z;
  const u16* A = z ? A1 : A0;
  const u16* BT = z ? BT1 : BT0;
  const float* bias = z ? bias1 : bias0;
  u16* Cv = z ? C1 : C0;
  const int t = threadIdx.x;
  const int lane = t & 63;
  const int w = t >> 6;
  const int wr = w >> 1, wc = w & 1;
  const int m0 = blockIdx.x * 128;
  const int n0 = blockIdx.y * 128;
  const int c16 = lane & 15, r16 = lane >> 4;

  f32x4_t acc[4][4] = {};

  for (int k0 = 0; k0 < K; k0 += BK) {
#pragma unroll
    for (int i = 0; i < 2; ++i) {
      const int idx = i * 256 + t;
      const int row = idx >> 2, ch = idx & 3;
      const int gch = ch ^ ((row >> 1) & 3);
      async_load16(A + (size_t)(m0 + row) * K + k0 + gch * 8,
                   (char*)sA + (i * 256 + w * 64) * 16);
    }
#pragma unroll
    for (int i = 0; i < 2; ++i) {
      const int idx = i * 256 + t;
      const int row = idx >> 2, ch = idx & 3;
      const int gch = ch ^ ((row >> 1) & 3);
      async_load16(BT + (size_t)(n0 + row) * K + k0 + gch * 8,
                   (char*)sB + (i * 256 + w * 64) * 16);
    }
    __syncthreads();

    bf16x8_t af[4], bfv[4];
#pragma unroll
    for (int m = 0; m < 4; ++m) {
      const int ra = wr * 64 + m * 16 + c16;
      af[m] = *(const bf16x8_t*)&sA[ra * BK + ((r16 ^ ((ra >> 1) & 3)) << 3)];
    }
#pragma unroll
    for (int n = 0; n < 4; ++n) {
      const int rb = wc * 64 + n * 16 + c16;
      bfv[n] = *(const bf16x8_t*)&sB[rb * BK + ((r16 ^ ((rb >> 1) & 3)) << 3)];
    }
#pragma unroll
    for (int m = 0; m < 4; ++m)
#pragma unroll
      for (int n = 0; n < 4; ++n)
        acc[m][n] = MFMA_BF16(af[m], bfv[n], acc[m][n], 0, 0, 0);
    __syncthreads();
  }

#pragma unroll
  for (int m = 0; m < 4; ++m) {
    const int row0 = m0 + wr * 64 + m * 16 + r16 * 4;
#pragma unroll
    for (int n = 0; n < 4; ++n) {
      const int col = n0 + wc * 64 + n * 16 + c16;
      const float bvl = bias[col];
#pragma unroll
      for (int i = 0; i < 4; ++i) {
        const float val = acc[m][n][i] + bvl;
        if (z)
          Cv[(size_t)col * 256 + row0 + i] = f2bf(val);   // vd^T layout [1024][256]
        else
          Cv[(size_t)(row0 + i) * 1024 + col] = f2bf(val);
      }
    }
  }
}

// ======== bf16-A K-loop (unchanged, out-GEMM) ========
#define GEMM256_KLOOP(A_, BT_)                                                          \
  const u16* Ab = (A_) + (size_t)bx * 256 * 1024;                                       \
  const u16* Bb = (BT_) + (size_t)by * 256 * 1024;                                      \
  stage64(Ab,                   lds,                 t);                                \
  stage64(Ab + 128 * 1024,      lds + 128 * 128,     t);                                \
  stage64(Bb,                   lds + 32768,         t);                                \
  stage64(Bb + 64 * 1024,       lds + 32768 + 8192,  t);                                \
  stage64(Bb + 128 * 1024,      lds + 32768 + 16384, t);                                \
  stage64(Bb + 192 * 1024,      lds + 32768 + 24576, t);                                \
  stage64(Ab + 64 * 1024,       lds + 64 * 128,      t);                                \
  stage64(Ab + 192 * 1024,      lds + 192 * 128,     t);                                \
  stage64(Ab + 64,              lds + 65536,         t);                                \
  stage64(Ab + 128 * 1024 + 64, lds + 65536 + 16384, t);                                \
  stage64(Bb + 64,              lds + 98304,         t);                                \
  stage64(Bb + 64 * 1024 + 64,  lds + 98304 + 8192,  t);                                \
  stage64(Bb + 128 * 1024 + 64, lds + 98304 + 16384, t);                                \
  stage64(Bb + 192 * 1024 + 64, lds + 98304 + 24576, t);                                \
  asm volatile("s_waitcnt vmcnt(6)" ::: "memory");                                      \
  __builtin_amdgcn_s_barrier();                                                         \
  for (int kt = 0; kt < 16; ++kt) {                                                     \
    const int slot = kt & 1;                                                            \
    const u16* sAs = (const u16*)(lds + slot * 65536);                                  \
    const u16* sBs = (const u16*)(lds + slot * 65536 + 32768);                          \
    char* sAn = lds + (slot ^ 1) * 65536;                                               \
    char* sAc = lds + slot * 65536;                                                     \
    char* sBc = lds + slot * 65536 + 32768;                                             \
    const int k1 = (kt < 15 ? kt + 1 : 15) * 64;                                        \
    const int k2 = (kt < 14 ? kt + 2 : 15) * 64;                                        \
    bf16x8_t af[4][2];                                                                  \
    _Pragma("unroll") for (int m = 0; m < 4; ++m) {                                     \
      const int row = wm * 128 + m * 16 + c16;                                          \
      _Pragma("unroll") for (int kk = 0; kk < 2; ++kk)                                  \
        af[m][kk] = *(const bf16x8_t*)&sAs[row * 64 + (((kk * 4 + r16) ^ c7) << 3)];    \
    }                                                                                   \
    _Pragma("unroll") for (int n = 0; n < 2; ++n) {                                     \
      const int row = wn * 64 + n * 16 + c16;                                           \
      _Pragma("unroll") for (int kk = 0; kk < 2; ++kk)                                  \
        bfr[n][kk] = *(const bf16x8_t*)&sBs[row * 64 + (((kk * 4 + r16) ^ c7) << 3)];   \
    }                                                                                   \
    stage64(Ab + (size_t)64 * 1024 + k1,  sAn + 64 * 128,  t);                          \
    stage64(Ab + (size_t)192 * 1024 + k1, sAn + 192 * 128, t);                          \
    asm volatile("" ::: "memory");                                                      \
    __builtin_amdgcn_s_barrier();                                                       \
    asm volatile("s_waitcnt lgkmcnt(0)" ::: "memory");                                  \
    __builtin_amdgcn_sched_barrier(0);                                                  \
    __builtin_amdgcn_s_setprio(1);                                                      \
    _Pragma("unroll") for (int m = 0; m < 4; ++m)                                       \
      _Pragma("unroll") for (int n = 0; n < 2; ++n)                                     \
        _Pragma("unroll") for (int kk = 0; kk < 2; ++kk)                                \
          acc[m][n] = MFMA_BF16(af[m][kk], bfr[n][kk], acc[m][n], 0, 0, 0);             \
    __builtin_amdgcn_s_setprio(0);                                                      \
    asm volatile("" ::: "memory");                                                      \
    __builtin_amdgcn_s_barrier();                                                       \
    _Pragma("unroll") for (int n = 2; n < 4; ++n) {                                     \
      const int row = wn * 64 + n * 16 + c16;                                           \
      _Pragma("unroll") for (int kk = 0; kk < 2; ++kk)                                  \
        bfr[n][kk] = *(const bf16x8_t*)&sBs[row * 64 + (((kk * 4 + r16) ^ c7) << 3)];   \
    }                                                                                   \
    stage64(Ab + k2,                      sAc,             t);                          \
    stage64(Ab + (size_t)128 * 1024 + k2, sAc + 128 * 128, t);                          \
    asm volatile("" ::: "memory");                                                      \
    __builtin_amdgcn_s_barrier();                                                       \
    asm volatile("s_waitcnt lgkmcnt(0)" ::: "memory");                                  \
    __builtin_amdgcn_sched_barrier(0);                                                  \
    __builtin_amdgcn_s_setprio(1);                                                      \
    _Pragma("unroll") for (int m = 0; m < 4; ++m)                                       \
      _Pragma("unroll") for (int n = 2; n < 4; ++n)                                     \
        _Pragma("unroll") for (int kk = 0; kk < 2; ++kk)                                \
          acc[m][n] = MFMA_BF16(af[m][kk], bfr[n][kk], acc[m][n], 0, 0, 0);             \
    __builtin_amdgcn_s_setprio(0);                                                      \
    asm volatile("s_waitcnt vmcnt(10)" ::: "memory");                                   \
    __builtin_amdgcn_s_barrier();                                                       \
    _Pragma("unroll") for (int m = 0; m < 4; ++m) {                                     \
      const int row = wm * 128 + 64 + m * 16 + c16;                                     \
      _Pragma("unroll") for (int kk = 0; kk < 2; ++kk)                                  \
        af[m][kk] = *(const bf16x8_t*)&sAs[row * 64 + (((kk * 4 + r16) ^ c7) << 3)];    \
    }                                                                                   \
    stage64(Bb + k2,                     sBc,        t);                                \
    stage64(Bb + (size_t)64 * 1024 + k2, sBc + 8192, t);                                \
    asm volatile("" ::: "memory");                                                      \
    __builtin_amdgcn_s_barrier();                                                       \
    asm volatile("s_waitcnt lgkmcnt(0)" ::: "memory");                                  \
    __builtin_amdgcn_sched_barrier(0);                                                  \
    __builtin_amdgcn_s_setprio(1);                                                      \
    _Pragma("unroll") for (int m = 0; m < 4; ++m)                                       \
      _Pragma("unroll") for (int n = 0; n < 2; ++n)                                     \
        _Pragma("unroll") for (int kk = 0; kk < 2; ++kk)                                \
          acc[4 + m][n] = MFMA_BF16(af[m][kk], bfr[n][kk], acc[4 + m][n], 0, 0, 0);     \
    __builtin_amdgcn_s_setprio(0);                                                      \
    asm volatile("" ::: "memory");                                                      \
    __builtin_amdgcn_s_barrier();                                                       \
    stage64(Bb + (size_t)128 * 1024 + k2, sBc + 16384, t);                              \
    stage64(Bb + (size_t)192 * 1024 + k2, sBc + 24576, t);                              \
    asm volatile("" ::: "memory");                                                      \
    __builtin_amdgcn_s_barrier();                                                       \
    __builtin_amdgcn_sched_barrier(0);                                                  \
    __builtin_amdgcn_s_setprio(1);                                                      \
    _Pragma("unroll") for (int m = 0; m < 4; ++m)                                       \
      _Pragma("unroll") for (int n = 2; n < 4; ++n)                                     \
        _Pragma("unroll") for (int kk = 0; kk < 2; ++kk)                                \
          acc[4 + m][n] = MFMA_BF16(af[m][kk], bfr[n][kk], acc[4 + m][n], 0, 0, 0);     \
    __builtin_amdgcn_s_setprio(0);                                                      \
    asm volatile("s_waitcnt vmcnt(8)" ::: "memory");                                    \
    __builtin_amdgcn_s_barrier();                                                       \
  }

// ======== fp32-A K-loop: A reg-staged via PLAIN HIP loads (compiler-managed waits),
// cvt+ds_write reproduces stage64's chunk-XOR layout; B via stage64. No manual in-loop
// vmcnt — loop-carried load waits are compiler-emitted (worst case over-drain, never race).
// Issue->consume: ra(A2A3,kt+2): p2 -> p0 of kt+1 (6 intervening vmem);
//                 rb(A0A1,kt+3): p3 -> p1 of kt+1 (2 intervening).
#define GEMM256_KLOOP_F32A(AF_, BT_)                                                    \
  const float* Af = (AF_) + (size_t)bx * 256 * 1024;                                    \
  const u16* Bb = (BT_) + (size_t)by * 256 * 1024;                                      \
  {                                                                                     \
    /* A(0) full + A0A1(1), synchronous */                                              \
    float4 x0 = LDA4(arow01, 0, 0), x1 = LDA4(arow01, 0, 1);                            \
    float4 x2 = LDA4(arow01, 0, 2), x3 = LDA4(arow01, 0, 3);                            \
    float4 y0 = LDA4(arow23, 0, 0), y1 = LDA4(arow23, 0, 1);                            \
    float4 y2 = LDA4(arow23, 0, 2), y3 = LDA4(arow23, 0, 3);                            \
    float4 z0 = LDA4(arow01, 64, 0), z1 = LDA4(arow01, 64, 1);                          \
    float4 z2 = LDA4(arow01, 64, 2), z3 = LDA4(arow01, 64, 3);                          \
    cvt_write_row(x0, x1, x2, x3, arow01, q4, lds);                                     \
    cvt_write_row(y0, y1, y2, y3, arow23, q4, lds);                                     \
    cvt_write_row(z0, z1, z2, z3, arow01, q4, lds + 65536);                             \
  }                                                                                     \
  stage64(Bb,                  lds + 32768,         t);                                 \
  stage64(Bb + 64 * 1024,      lds + 32768 + 8192,  t);                                 \
  stage64(Bb + 128 * 1024,     lds + 32768 + 16384, t);                                 \
  stage64(Bb + 192 * 1024,     lds + 32768 + 24576, t);                                 \
  asm volatile("" ::: "memory");                                                        \
  stage64(Bb + 64,              lds + 98304,         t);                                \
  stage64(Bb + 64 * 1024 + 64,  lds + 98304 + 8192,  t);                                \
  stage64(Bb + 128 * 1024 + 64, lds + 98304 + 16384, t);                                \
  stage64(Bb + 192 * 1024 + 64, lds + 98304 + 24576, t);                                \
  ra0 = LDA4(arow23, 64, 0); ra1 = LDA4(arow23, 64, 1);                                 \
  ra2 = LDA4(arow23, 64, 2); ra3 = LDA4(arow23, 64, 3);                                 \
  rb0 = LDA4(arow01, 128, 0); rb1 = LDA4(arow01, 128, 1);                               \
  rb2 = LDA4(arow01, 128, 2); rb3 = LDA4(arow01, 128, 3);                               \
  asm volatile("s_waitcnt lgkmcnt(0)" ::: "memory");                                    \
  asm volatile("s_waitcnt vmcnt(12)" ::: "memory"); /* B(0) done; B(1)+ra+rb fly */     \
  __builtin_amdgcn_s_barrier();                                                         \
  for (int kt = 0; kt < 16; ++kt) {                                                     \
    const int slot = kt & 1;                                                            \
    const u16* sAs = (const u16*)(lds + slot * 65536);                                  \
    const u16* sBs = (const u16*)(lds + slot * 65536 + 32768);                          \
    char* sAn = lds + (slot ^ 1) * 65536;                                               \
    char* sAc = lds + slot * 65536;                                                     \
    char* sBc = lds + slot * 65536 + 32768;                                             \
    const int rowN = arow23;  /* A2A3 target rows */                                    \
    const int k2 = (kt < 14 ? kt + 2 : 15) * 64;                                        \
    const int k3 = (kt < 13 ? kt + 3 : 15) * 64;                                        \
    bf16x8_t af[4][2];                                                                  \
    /* ---- phase 0 ---- */                                                             \
    _Pragma("unroll") for (int m = 0; m < 4; ++m) {                                     \
      const int row = wm * 128 + m * 16 + c16;                                          \
      _Pragma("unroll") for (int kk = 0; kk < 2; ++kk)                                  \
        af[m][kk] = *(const bf16x8_t*)&sAs[row * 64 + (((kk * 4 + r16) ^ c7) << 3)];    \
    }                                                                                   \
    _Pragma("unroll") for (int n = 0; n < 2; ++n) {                                     \
      const int row = wn * 64 + n * 16 + c16;                                           \
      _Pragma("unroll") for (int kk = 0; kk < 2; ++kk)                                  \
        bfr[n][kk] = *(const bf16x8_t*)&sBs[row * 64 + (((kk * 4 + r16) ^ c7) << 3)];   \
    }                                                                                   \
    cvt_write_row(ra0, ra1, ra2, ra3, rowN, q4, sAn); /* A2A3(kt+1) */                  \
    asm volatile("s_waitcnt lgkmcnt(0)" ::: "memory"); /* write visible pre-barrier */  \
    __builtin_amdgcn_s_barrier();                                                       \
    __builtin_amdgcn_sched_barrier(0);                                                  \
    __builtin_amdgcn_s_setprio(1);                                                      \
    _Pragma("unroll") for (int m = 0; m < 4; ++m)                                       \
      _Pragma("unroll") for (int n = 0; n < 2; ++n)                                     \
        _Pragma("unroll") for (int kk = 0; kk < 2; ++kk)                                \
          acc[m][n] = MFMA_BF16(af[m][kk], bfr[n][kk], acc[m][n], 0, 0, 0);             \
    __builtin_amdgcn_s_setprio(0);                                                      \
    asm volatile("" ::: "memory");                                                      \
    __builtin_amdgcn_s_barrier();                                                       \
    /* ---- phase 1 ---- */                                                             \
    _Pragma("unroll") for (int n = 2; n < 4; ++n) {                                     \
      const int row = wn * 64 + n * 16 + c16;                                           \
      _Pragma("unroll") for (int kk = 0; kk < 2; ++kk)                                  \
        bfr[n][kk] = *(const bf16x8_t*)&sBs[row * 64 + (((kk * 4 + r16) ^ c7) << 3)];   \
    }                                                                                   \
    cvt_write_row(rb0, rb1, rb2, rb3, arow01, q4, sAc); /* A0A1(kt+2) */                \
    asm volatile("s_waitcnt lgkmcnt(0)" ::: "memory");                                  \
    __builtin_amdgcn_s_barrier();                                                       \
    __builtin_amdgcn_sched_barrier(0);                                                  \
    __builtin_amdgcn_s_setprio(1);                                                      \
    _Pragma("unroll") for (int m = 0; m < 4; ++m)                                       \
      _Pragma("unroll") for (int n = 2; n < 4; ++n)                                     \
        _Pragma("unroll") for (int kk = 0; kk < 2; ++kk)                                \
          acc[m][n] = MFMA_BF16(af[m][kk], bfr[n][kk], acc[m][n], 0, 0, 0);             \
    __builtin_amdgcn_s_setprio(0);                                                      \
    asm volatile("" ::: "memory");                                                      \
    __builtin_amdgcn_s_barrier();                                                       \
    /* ---- phase 2 ---- */                                                             \
    _Pragma("unroll") for (int m = 0; m < 4; ++m) {                                     \
      const int row = wm * 128 + 64 + m * 16 + c16;                                     \
      _Pragma("unroll") for (int kk = 0; kk < 2; ++kk)                                  \
        af[m][kk] = *(const bf16x8_t*)&sAs[row * 64 + (((kk * 4 + r16) ^ c7) << 3)];    \
    }                                                                                   \
    stage64(Bb + k2,                     sBc,        t);                                \
    stage64(Bb + (size_t)64 * 1024 + k2, sBc + 8192, t);                                \
    ra0 = LDA4(arow23, k2, 0); ra1 = LDA4(arow23, k2, 1);                               \
    ra2 = LDA4(arow23, k2, 2); ra3 = LDA4(arow23, k2, 3);                               \
    asm volatile("" ::: "memory");                                                      \
    __builtin_amdgcn_s_barrier();                                                       \
    asm volatile("s_waitcnt lgkmcnt(0)" ::: "memory");                                  \
    __builtin_amdgcn_sched_barrier(0);                                                  \
    __builtin_amdgcn_s_setprio(1);                                                      \
    _Pragma("unroll") for (int m = 0; m < 4; ++m)                                       \
      _Pragma("unroll") for (int n = 0; n < 2; ++n)                                     \
        _Pragma("unroll") for (int kk = 0; kk < 2; ++kk)                                \
          acc[4 + m][n] = MFMA_BF16(af[m][kk], bfr[n][kk], acc[4 + m][n], 0, 0, 0);     \
    __builtin_amdgcn_s_setprio(0);                                                      \
    asm volatile("" ::: "memory");                                                      \
    __builtin_amdgcn_s_barrier();                                                       \
    /* ---- phase 3 ---- */                                                             \
    stage64(Bb + (size_t)128 * 1024 + k2, sBc + 16384, t);                              \
    stage64(Bb + (size_t)192 * 1024 + k2, sBc + 24576, t);                              \
    rb0 = LDA4(arow01, k3, 0); rb1 = LDA4(arow01, k3, 1);                               \
    rb2 = LDA4(arow01, k3, 2); rb3 = LDA4(arow01, k3, 3);                               \
    asm volatile("" ::: "memory");                                                      \
    __builtin_amdgcn_s_barrier();                                                       \
    __builtin_amdgcn_sched_barrier(0);                                                  \
    __builtin_amdgcn_s_setprio(1);                                                      \
    _Pragma("unroll") for (int m = 0; m < 4; ++m)                                       \
      _Pragma("unroll") for (int n = 2; n < 4; ++n)                                     \
        _Pragma("unroll") for (int kk = 0; kk < 2; ++kk)                                \
          acc[4 + m][n] = MFMA_BF16(af[m][kk], bfr[n][kk], acc[4 + m][n], 0, 0, 0);     \
    __builtin_amdgcn_s_setprio(0);                                                      \
    asm volatile("" ::: "memory");                                                      \
    __builtin_amdgcn_s_barrier();                                                       \
  }

// ---------------- 256x256 8-phase GEMM (bf16 A, fp32 C) ----------------
template <bool C_BF16>
__global__ __launch_bounds__(512) void gemm256(const u16* __restrict__ A,
                                               const u16* __restrict__ BT,
                                               const float* __restrict__ bias,
                                               void* __restrict__ Cv) {
  __shared__ u16 sAB[65536];
  char* lds = (char*)sAB;
  const int t = threadIdx.x;
  const int lane = t & 63;
  const int w = t >> 6;
  const int wm = w >> 2, wn = w & 3;
  const int c16 = lane & 15, r16 = lane >> 4, c7 = c16 & 7;
  const int tile = (blockIdx.x & 7) * 32 + (blockIdx.x >> 3);
  const int bx = tile >> 2, by = tile & 3;
  f32x4_t acc[8][4] = {};
  bf16x8_t bfr[4][2];
  GEMM256_KLOOP(A, BT)
#pragma unroll
  for (int m = 0; m < 8; ++m) {
    const int grow = bx * 256 + wm * 128 + m * 16 + r16 * 4;
#pragma unroll
    for (int n = 0; n < 4; ++n) {
      const int col = by * 256 + wn * 64 + n * 16 + c16;
      const float bvl = bias[col];
#pragma unroll
      for (int i = 0; i < 4; ++i) {
        const float val = acc[m][n][i] + bvl;
        if constexpr (C_BF16)
          ((u16*)Cv)[(size_t)(grow + i) * 1024 + col] = f2bf(val);
        else
          ((float*)Cv)[(size_t)(grow + i) * 1024 + col] = val;
      }
    }
  }
}

// ======== fused attention epilogue half (HALF is a LITERAL 0/1 -> all static idx) ========
#define ATTN_EPI_HALF(HALF)                                                              \
  {                                                                                      \
    asm volatile("s_waitcnt lgkmcnt(0)" ::: "memory");                                   \
    _Pragma("unroll") for (int m = 0; m < 4; ++m)                                        \
      _Pragma("unroll") for (int nq = 0; nq < 4; ++nq) {                                 \
        const int d = nq * 16 + c16;                                                     \
        const float bvl = bias[n_head * 64 + d];                                         \
        _Pragma("unroll") for (int i = 0; i < 4; ++i) {                                  \
          const int row = m * 16 + r16 * 4 + i;                                          \
          qh[(row * 128 + ((d * 2) ^ ((row & 7) << 4))) >> 1] =                          \
              f2bf(acc[HALF * 4 + m][nq][i] + bvl);                                      \
        }                                                                                \
      }                                                                                  \
    if (HALF == 0) {                                                                     \
      asm volatile("s_waitcnt vmcnt(0) lgkmcnt(0)" ::: "memory");                        \
      __builtin_amdgcn_s_barrier();                                                      \
    } else {                                                                             \
      asm volatile("s_waitcnt lgkmcnt(0)" ::: "memory");                                 \
    }                                                                                    \
    bf16x8_t aq[4][2];                                                                   \
    _Pragma("unroll") for (int st = 0; st < 4; ++st) {                                   \
      const int row = st * 16 + c16;                                                     \
      const int rsw = (row & 7) << 4;                                                    \
      _Pragma("unroll") for (int dt = 0; dt < 2; ++dt)                                   \
        aq[st][dt] =                                                                     \
            *(const bf16x8_t*)&qh[(row * 128 + ((dt * 64 + r16 * 16) ^ rsw)) >> 1];      \
    }                                                                                    \
    asm volatile("s_waitcnt lgkmcnt(0)" ::: "memory");                                   \
    __builtin_amdgcn_sched_barrier(0);                                                   \
    u16* sP = qh;                                                                        \
    _Pragma("unroll") for (int st = 0; st < 4; ++st) {                                   \
      f32x4_t accs[4];                                                                   \
      _Pragma("unroll") for (int nn = 0; nn < 4; ++nn) {                                 \
        const u16* kr = &kdw[(nn * 16 + c16) * 64];                                      \
        bf16x8_t b0 = *(const bf16x8_t*)&kr[((r16 * 16) ^ swz) >> 1];                    \
        bf16x8_t b1 = *(const bf16x8_t*)&kr[((64 + r16 * 16) ^ swz) >> 1];               \
        f32x4_t a = {0.f, 0.f, 0.f, 0.f};                                                \
        a = MFMA_BF16(aq[st][0], b0, a, 0, 0, 0);                                        \
        a = MFMA_BF16(aq[st][1], b1, a, 0, 0, 0);                                        \
        accs[nn] = a;                                                                    \
      }                                                                                  \
      float ex[4][4], rs[4];                                                             \
      _Pragma("unroll") for (int i = 0; i < 4; ++i) {                                    \
        float mx = fmaxf(fmaxf(accs[0][i], accs[1][i]), fmaxf(accs[2][i], accs[3][i]));  \
        _Pragma("unroll") for (int off = 1; off < 16; off <<= 1)                         \
          mx = fmaxf(mx, __shfl_xor(mx, off));                                           \
        mx *= 0.125f;                                                                    \
        float s = 0.f;                                                                   \
        _Pragma("unroll") for (int nn = 0; nn < 4; ++nn) {                               \
          float e = __expf(accs[nn][i] * 0.125f - mx);                                   \
          ex[nn][i] = e;                                                                 \
          s += e;                                                                        \
        }                                                                                \
        _Pragma("unroll") for (int off = 1; off < 16; off <<= 1)                         \
          s += __shfl_xor(s, off);                                                       \
        rs[i] = 1.f / s;                                                                 \
      }                                                                                  \
      _Pragma("unroll") for (int i = 0; i < 4; ++i) {                                    \
        const int row = r16 * 4 + i;                                                     \
        const int rsw = (row & 7) << 4;                                                  \
        _Pragma("unroll") for (int nn = 0; nn < 4; ++nn)                                 \
          sP[row * 64 + (((nn * 32 + c16 * 2) ^ rsw) >> 1)] = f2bf(ex[nn][i]);           \
      }                                                                                  \
      asm volatile("s_waitcnt lgkmcnt(0)" ::: "memory");                                 \
      bf16x8_t pa0 = *(const bf16x8_t*)&sP[c16 * 64 + (((r16 * 16) ^ swz) >> 1)];        \
      bf16x8_t pa1 = *(const bf16x8_t*)&sP[c16 * 64 + (((64 + r16 * 16) ^ swz) >> 1)];   \
      f32x4_t accv[4];                                                                   \
      _Pragma("unroll") for (int dt = 0; dt < 4; ++dt) {                                 \
        const u16* vr = &vdw[(dt * 16 + c16) * 64];                                      \
        bf16x8_t v0 = *(const bf16x8_t*)&vr[((r16 * 16) ^ swz) >> 1];                    \
        bf16x8_t v1 = *(const bf16x8_t*)&vr[((64 + r16 * 16) ^ swz) >> 1];               \
        f32x4_t a = {0.f, 0.f, 0.f, 0.f};                                                \
        a = MFMA_BF16(pa0, v0, a, 0, 0, 0);                                              \
        a = MFMA_BF16(pa1, v1, a, 0, 0, 0);                                              \
        accv[dt] = a;                                                                    \
      }                                                                                  \
      _Pragma("unroll") for (int i = 0; i < 4; ++i) {                                    \
        const int row = r16 * 4 + i;                                                     \
        const int rsw = (row & 7) << 4;                                                  \
        _Pragma("unroll") for (int dt = 0; dt < 4; ++dt)                                 \
          sP[row * 64 + (((dt * 32 + c16 * 2) ^ rsw) >> 1)] = f2bf(accv[dt][i] * rs[i]); \
      }                                                                                  \
      asm volatile("s_waitcnt lgkmcnt(0)" ::: "memory");                                 \
      const int srow_base = b * 4096 + s0b + wm * 128 + HALF * 64 + st * 16;             \
      _Pragma("unroll") for (int r = 0; r < 2; ++r) {                                    \
        const int row = r * 8 + (lane >> 3);                                             \
        const int cb = ((lane & 7) * 16) ^ ((row & 7) << 4);                             \
        bf16x8_t vv = *(const bf16x8_t*)&sP[row * 64 + (cb >> 1)];                       \
        *(bf16x8_t*)(av + (size_t)(srow_base + row) * 1024 + n_head * 64 +               \
                     (lane & 7) * 8) = vv;                                               \
      }                                                                                  \
    }                                                                                    \
  }

// ---------------- 256x256 q-GEMM (fp32 A direct, plain-HIP staged) + FUSED attention ----------------
__global__ __launch_bounds__(512) void gemm256_attn(const float* __restrict__ Aq,
                                                    const u16* __restrict__ BT,
                                                    const float* __restrict__ bias,
                                                    const u16* __restrict__ kdb,
                                                    const u16* __restrict__ vdTb,
                                                    u16* __restrict__ av) {
  __shared__ u16 sAB[65536];
  char* lds = (char*)sAB;
  const int t = threadIdx.x;
  const int lane = t & 63;
  const int w = t >> 6;
  const int wm = w >> 2, wn = w & 3;
  const int c16 = lane & 15, r16 = lane >> 4, c7 = c16 & 7;
  const int tile = (blockIdx.x & 7) * 32 + (blockIdx.x >> 3);
  const int bx = tile >> 2, by = tile & 3;
  // A reg-staging mapping: thread -> (row, 16-col quarter)
  const int ar = t >> 2;                          // 0..127
  const int q4 = t & 3;                           // 16-col quarter
  const int arow01 = (ar < 64) ? ar : 64 + ar;    // rows 0-63, 128-191 (A0,A1)
  const int arow23 = arow01 + 64;                 // rows 64-127, 192-255 (A2,A3)
#define LDA4(row, koff, j) \
  (*(const float4*)(Af + (size_t)(row) * 1024 + (koff) + q4 * 16 + (j) * 4))
  float4 ra0, ra1, ra2, ra3, rb0, rb1, rb2, rb3;
  f32x4_t acc[8][4] = {};
  bf16x8_t bfr[4][2];
  GEMM256_KLOOP_F32A(Aq, BT)
#undef LDA4

  // ---- fused attention epilogue ----
  asm volatile("s_waitcnt vmcnt(0) lgkmcnt(0)" ::: "memory");  // drain tail loads
  __builtin_amdgcn_s_barrier();                                // LDS free for reuse

  const int b = bx >> 4;
  const int s0b = (bx & 15) * 256;
  char* kdL = lds + 65536;          // 32KB: 4 heads x [64k][64d] (swizzled)
  char* vdL = lds + 65536 + 32768;  // 32KB: 4 heads x [64d][64k] (swizzled)
  {
    const int kk = t >> 3;
    const int colb = ((t & 7) ^ (kk & 7)) << 4;
#pragma unroll
    for (int h = 0; h < 4; ++h) {
      const int n = by * 4 + h;
      async_load16((const char*)kdb + (size_t)(b * 64 + kk) * 2048 + n * 128 + colb,
                   kdL + h * 8192 + (t >> 6) * 1024);
      async_load16((const char*)vdTb + (size_t)(n * 64 + kk) * 512 + b * 128 + colb,
                   vdL + h * 8192 + (t >> 6) * 1024);
    }
  }
  u16* qh = (u16*)(lds + w * 8192);  // per-wave 8KB q half-tile region
  const int n_head = by * 4 + wn;
  const u16* kdw = (const u16*)(kdL + wn * 8192);
  const u16* vdw = (const u16*)(vdL + wn * 8192);
  const int swz = (c16 & 7) << 4;

  ATTN_EPI_HALF(0)
  ATTN_EPI_HALF(1)
}

extern "C" void kernel_launch(void* const* d_in, const int* in_sizes, int n_in,
                              void* d_out, int out_size, void* d_ws, size_t ws_size,
                              hipStream_t stream) {
  (void)in_sizes; (void)n_in; (void)out_size; (void)ws_size;
  const float* query = (const float*)d_in[0];
  const float* key   = (const float*)d_in[1];
  const float* value = (const float*)d_in[2];
  const float* Wq = (const float*)d_in[3];
  const float* bq = (const float*)d_in[4];
  const float* Wk = (const float*)d_in[5];
  const float* bk = (const float*)d_in[6];
  const float* Wv = (const float*)d_in[7];
  const float* bv = (const float*)d_in[8];
  const float* Wo = (const float*)d_in[9];
  const float* bo = (const float*)d_in[10];
  float* out = (float*)d_out;

  char* ws = (char*)d_ws;
  const size_t MB = 1024 * 1024;
  u16* WqT    = (u16*)(ws + 0 * MB);
  u16* WkT    = (u16*)(ws + 2 * MB);
  u16* WvT    = (u16*)(ws + 4 * MB);
  u16* WoT    = (u16*)(ws + 6 * MB);
  u16* keyd   = (u16*)(ws + 8 * MB);
  u16* valued = (u16*)(ws + 8 * MB + 512 * 1024);
  u16* kdb    = (u16*)(ws + 9 * MB);
  u16* vdTb   = (u16*)(ws + 9 * MB + 512 * 1024);
  u16* avb    = (u16*)(ws + 10 * MB);             // 32MB bf16 [16384][1024]

  // streaming pre-pass: downsample + weight transposes (query consumed fp32 by q-GEMM)
  fused_stream<<<1536, 512, 0, stream>>>(key, value, Wq, Wk, Wv, Wo,
                                         keyd, valued, WqT, WkT, WvT, WoT);

  gemm_kv<<<dim3(2, 8, 2), 256, 0, stream>>>(keyd, valued, WkT, WvT, bk, bv, kdb, vdTb);

  gemm256_attn<<<256, 512, 0, stream>>>(query, WqT, bq, kdb, vdTb, avb);
  gemm256<false><<<256, 512, 0, stream>>>(avb, WoT, bo, out);
}

// Round 14
// 162.576 us; speedup vs baseline: 1.0785x; 1.0785x over previous
//
#include <hip/hip_runtime.h>

typedef unsigned short u16;
typedef unsigned int u32;
typedef __attribute__((ext_vector_type(8))) short bf16x8_t;
typedef __attribute__((ext_vector_type(4))) float f32x4_t;

// Problem constants: B=4, S=4096, H=1024, N=16, D=64, K-pool=64

#define MFMA_BF16 __builtin_amdgcn_mfma_f32_16x16x32_bf16

__device__ __forceinline__ u16 f2bf(float f) {
  union { float f; u32 u; } a; a.f = f;
  u32 u = a.u;
  u32 r = (u + 0x7FFFu + ((u >> 16) & 1u)) >> 16;  // RNE
  return (u16)r;
}

__device__ __forceinline__ void async_load16(const void* g, void* l) {
  __builtin_amdgcn_global_load_lds(
      (const __attribute__((address_space(1))) void*)g,
      (__attribute__((address_space(3))) void*)l, 16, 0, 0);
}

// stage 64 rows x 128B (8KB, one issue/thread) with chunk pre-swizzle
__device__ __forceinline__ void stage64(const u16* __restrict__ src,
                                        char* lds_base, int t) {
  const int r = t >> 3;
  const int gch = (t & 7) ^ (r & 7);
  async_load16(src + (size_t)r * 1024 + gch * 8, lds_base + (t >> 6) * 1024);
}

// ---------------- fused streaming pre-pass: downsample + query-cvt + 4x transpose ----------------
// z in [0,512): downsample key/value bucket; z in [512,4608): query fp32->bf16 chunk;
// z in [4608,5632): weight transpose tile. Streaming reads use nontemporal hints
// (touched exactly once) to avoid cache-fill-path pollution. NOTE: nontemporal
// builtins require ext-vector types (f32x4_t), not HIP's float4 struct.
__global__ __launch_bounds__(512) void fused_stream(
    const float* __restrict__ query, const float* __restrict__ key,
    const float* __restrict__ value, const float* __restrict__ W0,
    const float* __restrict__ W1, const float* __restrict__ W2,
    const float* __restrict__ W3, u16* __restrict__ qcvt, u16* __restrict__ keyd,
    u16* __restrict__ valued, u16* __restrict__ T0, u16* __restrict__ T1,
    u16* __restrict__ T2, u16* __restrict__ T3) {
  __shared__ char smem[32768];
  const int z = blockIdx.x;
  const int t = threadIdx.x;
  if (z < 512) {
    // ---- downsample: contiguous 256KB region, wave-per-8-rows, deep-batched nt loads ----
    f32x4_t (*part)[256] = (f32x4_t(*)[256])smem;  // [8][256] f32x4 = 32KB
    const int bkk = z & 255;
    const float* x = (z >= 256) ? value : key;
    u16* xd = (z >= 256) ? valued : keyd;
    const int lane = t & 63, w = t >> 6;
    const float* base = x + (size_t)bkk * 65536 + (size_t)w * 8 * 1024;
#define LD4(j, s) \
  __builtin_nontemporal_load((const f32x4_t*)(base + (size_t)(j) * 1024 + ((s) * 64 + lane) * 4))
    f32x4_t a0 = {0.f, 0.f, 0.f, 0.f}, a1 = a0, a2 = a0, a3 = a0;
    f32x4_t u0 = LD4(0, 0), u1 = LD4(0, 1), u2 = LD4(0, 2), u3 = LD4(0, 3);
    f32x4_t u4 = LD4(1, 0), u5 = LD4(1, 1), u6 = LD4(1, 2), u7 = LD4(1, 3);
    f32x4_t v0 = LD4(2, 0), v1 = LD4(2, 1), v2 = LD4(2, 2), v3 = LD4(2, 3);
    f32x4_t v4 = LD4(3, 0), v5 = LD4(3, 1), v6 = LD4(3, 2), v7 = LD4(3, 3);
    a0 += u0; a1 += u1; a2 += u2; a3 += u3;
    a0 += u4; a1 += u5; a2 += u6; a3 += u7;
    u0 = LD4(4, 0); u1 = LD4(4, 1); u2 = LD4(4, 2); u3 = LD4(4, 3);
    u4 = LD4(5, 0); u5 = LD4(5, 1); u6 = LD4(5, 2); u7 = LD4(5, 3);
    a0 += v0; a1 += v1; a2 += v2; a3 += v3;
    a0 += v4; a1 += v5; a2 += v6; a3 += v7;
    v0 = LD4(6, 0); v1 = LD4(6, 1); v2 = LD4(6, 2); v3 = LD4(6, 3);
    v4 = LD4(7, 0); v5 = LD4(7, 1); v6 = LD4(7, 2); v7 = LD4(7, 3);
    a0 += u0; a1 += u1; a2 += u2; a3 += u3;
    a0 += u4; a1 += u5; a2 += u6; a3 += u7;
    a0 += v0; a1 += v1; a2 += v2; a3 += v3;
    a0 += v4; a1 += v5; a2 += v6; a3 += v7;
#undef LD4
    part[w][0 * 64 + lane] = a0;
    part[w][1 * 64 + lane] = a1;
    part[w][2 * 64 + lane] = a2;
    part[w][3 * 64 + lane] = a3;
    __syncthreads();
    if (t < 256) {
      f32x4_t s = {0.f, 0.f, 0.f, 0.f};
#pragma unroll
      for (int w2 = 0; w2 < 8; ++w2) s += part[w2][t];
      ushort4 r;
      r.x = f2bf(s[0] * 0.015625f);
      r.y = f2bf(s[1] * 0.015625f);
      r.z = f2bf(s[2] * 0.015625f);
      r.w = f2bf(s[3] * 0.015625f);
      *(ushort4*)(xd + (size_t)bkk * 1024 + t * 4) = r;  // cached: re-read by gemm_kv
    }
  } else if (z < 4608) {
    // ---- query fp32 -> bf16, 4096 elems per block (nt read; cached write) ----
    const size_t i = ((size_t)(z - 512) * 512 + t) * 8;
    const f32x4_t a = __builtin_nontemporal_load((const f32x4_t*)(query + i));
    const f32x4_t b = __builtin_nontemporal_load((const f32x4_t*)(query + i + 4));
    bf16x8_t o;
    o[0] = (short)f2bf(a[0]); o[1] = (short)f2bf(a[1]);
    o[2] = (short)f2bf(a[2]); o[3] = (short)f2bf(a[3]);
    o[4] = (short)f2bf(b[0]); o[5] = (short)f2bf(b[1]);
    o[6] = (short)f2bf(b[2]); o[7] = (short)f2bf(b[3]);
    *(bf16x8_t*)(qcvt + i) = o;
  } else {
    // ---- weight transpose 64x64 tile (nt fp32 read -> bf16 transposed, cached write) ----
    float (*tile)[65] = (float(*)[65])smem;  // [64][65]
    const int blk = z - 4608;
    const int wsel = blk >> 8, tidx = blk & 255;
    const float* W = (wsel == 0) ? W0 : (wsel == 1) ? W1 : (wsel == 2) ? W2 : W3;
    u16* WT = (wsel == 0) ? T0 : (wsel == 1) ? T1 : (wsel == 2) ? T2 : T3;
    const int tr = (tidx >> 4) * 64;
    const int tc = (tidx & 15) * 64;
#pragma unroll
    for (int i = 0; i < 8; ++i) {
      int idx = i * 512 + t;
      int r = idx >> 6, c = idx & 63;
      tile[r][c] = __builtin_nontemporal_load(W + (size_t)(tr + r) * 1024 + tc + c);
    }
    __syncthreads();
#pragma unroll
    for (int i = 0; i < 8; ++i) {
      int idx = i * 512 + t;
      int r = idx >> 6, c = idx & 63;
      WT[(size_t)(tc + r) * 1024 + tr + c] = f2bf(tile[c][r]);
    }
  }
}

// ---------------- fused small GEMMs (M=256): kd and vd^T in one launch ----------------
__global__ __launch_bounds__(256) void gemm_kv(const u16* __restrict__ A0,
                                               const u16* __restrict__ A1,
                                               const u16* __restrict__ BT0,
                                               const u16* __restrict__ BT1,
                                               const float* __restrict__ bias0,
                                               const float* __restrict__ bias1,
                                               u16* __restrict__ C0,
                                               u16* __restrict__ C1) {
  constexpr int K = 1024, BK = 32;
  __shared__ u16 sA[128 * BK];
  __shared__ u16 sB[128 * BK];
  const int z = blockIdx.z;
  const u16* A = z ? A1 : A0;
  const u16* BT = z ? BT1 : BT0;
  const float* bias = z ? bias1 : bias0;
  u16* Cv = z ? C1 : C0;
  const int t = threadIdx.x;
  const int lane = t & 63;
  const int w = t >> 6;
  const int wr = w >> 1, wc = w & 1;
  const int m0 = blockIdx.x * 128;
  const int n0 = blockIdx.y * 128;
  const int c16 = lane & 15, r16 = lane >> 4;

  f32x4_t acc[4][4] = {};

  for (int k0 = 0; k0 < K; k0 += BK) {
#pragma unroll
    for (int i = 0; i < 2; ++i) {
      const int idx = i * 256 + t;
      const int row = idx >> 2, ch = idx & 3;
      const int gch = ch ^ ((row >> 1) & 3);
      async_load16(A + (size_t)(m0 + row) * K + k0 + gch * 8,
                   (char*)sA + (i * 256 + w * 64) * 16);
    }
#pragma unroll
    for (int i = 0; i < 2; ++i) {
      const int idx = i * 256 + t;
      const int row = idx >> 2, ch = idx & 3;
      const int gch = ch ^ ((row >> 1) & 3);
      async_load16(BT + (size_t)(n0 + row) * K + k0 + gch * 8,
                   (char*)sB + (i * 256 + w * 64) * 16);
    }
    __syncthreads();

    bf16x8_t af[4], bfv[4];
#pragma unroll
    for (int m = 0; m < 4; ++m) {
      const int ra = wr * 64 + m * 16 + c16;
      af[m] = *(const bf16x8_t*)&sA[ra * BK + ((r16 ^ ((ra >> 1) & 3)) << 3)];
    }
#pragma unroll
    for (int n = 0; n < 4; ++n) {
      const int rb = wc * 64 + n * 16 + c16;
      bfv[n] = *(const bf16x8_t*)&sB[rb * BK + ((r16 ^ ((rb >> 1) & 3)) << 3)];
    }
#pragma unroll
    for (int m = 0; m < 4; ++m)
#pragma unroll
      for (int n = 0; n < 4; ++n)
        acc[m][n] = MFMA_BF16(af[m], bfv[n], acc[m][n], 0, 0, 0);
    __syncthreads();
  }

#pragma unroll
  for (int m = 0; m < 4; ++m) {
    const int row0 = m0 + wr * 64 + m * 16 + r16 * 4;
#pragma unroll
    for (int n = 0; n < 4; ++n) {
      const int col = n0 + wc * 64 + n * 16 + c16;
      const float bvl = bias[col];
#pragma unroll
      for (int i = 0; i < 4; ++i) {
        const float val = acc[m][n][i] + bvl;
        if (z)
          Cv[(size_t)col * 256 + row0 + i] = f2bf(val);   // vd^T layout [1024][256]
        else
          Cv[(size_t)(row0 + i) * 1024 + col] = f2bf(val);
      }
    }
  }
}

// ======== K-loop macro shared by gemm256 and gemm256_attn (identical schedule) ========
#define GEMM256_KLOOP(A_, BT_)                                                          \
  const u16* Ab = (A_) + (size_t)bx * 256 * 1024;                                       \
  const u16* Bb = (BT_) + (size_t)by * 256 * 1024;                                      \
  stage64(Ab,                   lds,                 t);                                \
  stage64(Ab + 128 * 1024,      lds + 128 * 128,     t);                                \
  stage64(Bb,                   lds + 32768,         t);                                \
  stage64(Bb + 64 * 1024,       lds + 32768 + 8192,  t);                                \
  stage64(Bb + 128 * 1024,      lds + 32768 + 16384, t);                                \
  stage64(Bb + 192 * 1024,      lds + 32768 + 24576, t);                                \
  stage64(Ab + 64 * 1024,       lds + 64 * 128,      t);                                \
  stage64(Ab + 192 * 1024,      lds + 192 * 128,     t);                                \
  stage64(Ab + 64,              lds + 65536,         t);                                \
  stage64(Ab + 128 * 1024 + 64, lds + 65536 + 16384, t);                                \
  stage64(Bb + 64,              lds + 98304,         t);                                \
  stage64(Bb + 64 * 1024 + 64,  lds + 98304 + 8192,  t);                                \
  stage64(Bb + 128 * 1024 + 64, lds + 98304 + 16384, t);                                \
  stage64(Bb + 192 * 1024 + 64, lds + 98304 + 24576, t);                                \
  asm volatile("s_waitcnt vmcnt(6)" ::: "memory");                                      \
  __builtin_amdgcn_s_barrier();                                                         \
  for (int kt = 0; kt < 16; ++kt) {                                                     \
    const int slot = kt & 1;                                                            \
    const u16* sAs = (const u16*)(lds + slot * 65536);                                  \
    const u16* sBs = (const u16*)(lds + slot * 65536 + 32768);                          \
    char* sAn = lds + (slot ^ 1) * 65536;                                               \
    char* sAc = lds + slot * 65536;                                                     \
    char* sBc = lds + slot * 65536 + 32768;                                             \
    const int k1 = (kt < 15 ? kt + 1 : 15) * 64;                                        \
    const int k2 = (kt < 14 ? kt + 2 : 15) * 64;                                        \
    bf16x8_t af[4][2];                                                                  \
    _Pragma("unroll") for (int m = 0; m < 4; ++m) {                                     \
      const int row = wm * 128 + m * 16 + c16;                                          \
      _Pragma("unroll") for (int kk = 0; kk < 2; ++kk)                                  \
        af[m][kk] = *(const bf16x8_t*)&sAs[row * 64 + (((kk * 4 + r16) ^ c7) << 3)];    \
    }                                                                                   \
    _Pragma("unroll") for (int n = 0; n < 2; ++n) {                                     \
      const int row = wn * 64 + n * 16 + c16;                                           \
      _Pragma("unroll") for (int kk = 0; kk < 2; ++kk)                                  \
        bfr[n][kk] = *(const bf16x8_t*)&sBs[row * 64 + (((kk * 4 + r16) ^ c7) << 3)];   \
    }                                                                                   \
    stage64(Ab + (size_t)64 * 1024 + k1,  sAn + 64 * 128,  t);                          \
    stage64(Ab + (size_t)192 * 1024 + k1, sAn + 192 * 128, t);                          \
    asm volatile("" ::: "memory");                                                      \
    __builtin_amdgcn_s_barrier();                                                       \
    asm volatile("s_waitcnt lgkmcnt(0)" ::: "memory");                                  \
    __builtin_amdgcn_sched_barrier(0);                                                  \
    __builtin_amdgcn_s_setprio(1);                                                      \
    _Pragma("unroll") for (int m = 0; m < 4; ++m)                                       \
      _Pragma("unroll") for (int n = 0; n < 2; ++n)                                     \
        _Pragma("unroll") for (int kk = 0; kk < 2; ++kk)                                \
          acc[m][n] = MFMA_BF16(af[m][kk], bfr[n][kk], acc[m][n], 0, 0, 0);             \
    __builtin_amdgcn_s_setprio(0);                                                      \
    asm volatile("" ::: "memory");                                                      \
    __builtin_amdgcn_s_barrier();                                                       \
    _Pragma("unroll") for (int n = 2; n < 4; ++n) {                                     \
      const int row = wn * 64 + n * 16 + c16;                                           \
      _Pragma("unroll") for (int kk = 0; kk < 2; ++kk)                                  \
        bfr[n][kk] = *(const bf16x8_t*)&sBs[row * 64 + (((kk * 4 + r16) ^ c7) << 3)];   \
    }                                                                                   \
    stage64(Ab + k2,                      sAc,             t);                          \
    stage64(Ab + (size_t)128 * 1024 + k2, sAc + 128 * 128, t);                          \
    asm volatile("" ::: "memory");                                                      \
    __builtin_amdgcn_s_barrier();                                                       \
    asm volatile("s_waitcnt lgkmcnt(0)" ::: "memory");                                  \
    __builtin_amdgcn_sched_barrier(0);                                                  \
    __builtin_amdgcn_s_setprio(1);                                                      \
    _Pragma("unroll") for (int m = 0; m < 4; ++m)                                       \
      _Pragma("unroll") for (int n = 2; n < 4; ++n)                                     \
        _Pragma("unroll") for (int kk = 0; kk < 2; ++kk)                                \
          acc[m][n] = MFMA_BF16(af[m][kk], bfr[n][kk], acc[m][n], 0, 0, 0);             \
    __builtin_amdgcn_s_setprio(0);                                                      \
    asm volatile("s_waitcnt vmcnt(10)" ::: "memory");                                   \
    __builtin_amdgcn_s_barrier();                                                       \
    _Pragma("unroll") for (int m = 0; m < 4; ++m) {                                     \
      const int row = wm * 128 + 64 + m * 16 + c16;                                     \
      _Pragma("unroll") for (int kk = 0; kk < 2; ++kk)                                  \
        af[m][kk] = *(const bf16x8_t*)&sAs[row * 64 + (((kk * 4 + r16) ^ c7) << 3)];    \
    }                                                                                   \
    stage64(Bb + k2,                     sBc,        t);                                \
    stage64(Bb + (size_t)64 * 1024 + k2, sBc + 8192, t);                                \
    asm volatile("" ::: "memory");                                                      \
    __builtin_amdgcn_s_barrier();                                                       \
    asm volatile("s_waitcnt lgkmcnt(0)" ::: "memory");                                  \
    __builtin_amdgcn_sched_barrier(0);                                                  \
    __builtin_amdgcn_s_setprio(1);                                                      \
    _Pragma("unroll") for (int m = 0; m < 4; ++m)                                       \
      _Pragma("unroll") for (int n = 0; n < 2; ++n)                                     \
        _Pragma("unroll") for (int kk = 0; kk < 2; ++kk)                                \
          acc[4 + m][n] = MFMA_BF16(af[m][kk], bfr[n][kk], acc[4 + m][n], 0, 0, 0);     \
    __builtin_amdgcn_s_setprio(0);                                                      \
    asm volatile("" ::: "memory");                                                      \
    __builtin_amdgcn_s_barrier();                                                       \
    stage64(Bb + (size_t)128 * 1024 + k2, sBc + 16384, t);                              \
    stage64(Bb + (size_t)192 * 1024 + k2, sBc + 24576, t);                              \
    asm volatile("" ::: "memory");                                                      \
    __builtin_amdgcn_s_barrier();                                                       \
    __builtin_amdgcn_sched_barrier(0);                                                  \
    __builtin_amdgcn_s_setprio(1);                                                      \
    _Pragma("unroll") for (int m = 0; m < 4; ++m)                                       \
      _Pragma("unroll") for (int n = 2; n < 4; ++n)                                     \
        _Pragma("unroll") for (int kk = 0; kk < 2; ++kk)                                \
          acc[4 + m][n] = MFMA_BF16(af[m][kk], bfr[n][kk], acc[4 + m][n], 0, 0, 0);     \
    __builtin_amdgcn_s_setprio(0);                                                      \
    asm volatile("s_waitcnt vmcnt(8)" ::: "memory");                                    \
    __builtin_amdgcn_s_barrier();                                                       \
  }

// ---------------- 256x256 8-phase GEMM (plain epilogue; fp32 C via nt stores) ----------------
template <bool C_BF16>
__global__ __launch_bounds__(512) void gemm256(const u16* __restrict__ A,
                                               const u16* __restrict__ BT,
                                               const float* __restrict__ bias,
                                               void* __restrict__ Cv) {
  __shared__ u16 sAB[65536];
  char* lds = (char*)sAB;
  const int t = threadIdx.x;
  const int lane = t & 63;
  const int w = t >> 6;
  const int wm = w >> 2, wn = w & 3;
  const int c16 = lane & 15, r16 = lane >> 4, c7 = c16 & 7;
  const int tile = (blockIdx.x & 7) * 32 + (blockIdx.x >> 3);
  const int bx = tile >> 2, by = tile & 3;
  f32x4_t acc[8][4] = {};
  bf16x8_t bfr[4][2];
  GEMM256_KLOOP(A, BT)
#pragma unroll
  for (int m = 0; m < 8; ++m) {
    const int grow = bx * 256 + wm * 128 + m * 16 + r16 * 4;
#pragma unroll
    for (int n = 0; n < 4; ++n) {
      const int col = by * 256 + wn * 64 + n * 16 + c16;
      const float bvl = bias[col];
#pragma unroll
      for (int i = 0; i < 4; ++i) {
        const float val = acc[m][n][i] + bvl;
        if constexpr (C_BF16)
          ((u16*)Cv)[(size_t)(grow + i) * 1024 + col] = f2bf(val);
        else
          __builtin_nontemporal_store(val, (float*)Cv + (size_t)(grow + i) * 1024 + col);
      }
    }
  }
}

// ======== fused attention epilogue half (HALF is a LITERAL 0/1 -> all static idx) ========
#define ATTN_EPI_HALF(HALF)                                                              \
  {                                                                                      \
    asm volatile("s_waitcnt lgkmcnt(0)" ::: "memory");                                   \
    _Pragma("unroll") for (int m = 0; m < 4; ++m)                                        \
      _Pragma("unroll") for (int nq = 0; nq < 4; ++nq) {                                 \
        const int d = nq * 16 + c16;                                                     \
        const float bvl = bias[n_head * 64 + d];                                         \
        _Pragma("unroll") for (int i = 0; i < 4; ++i) {                                  \
          const int row = m * 16 + r16 * 4 + i;                                          \
          qh[(row * 128 + ((d * 2) ^ ((row & 7) << 4))) >> 1] =                          \
              f2bf(acc[HALF * 4 + m][nq][i] + bvl);                                      \
        }                                                                                \
      }                                                                                  \
    if (HALF == 0) {                                                                     \
      asm volatile("s_waitcnt vmcnt(0) lgkmcnt(0)" ::: "memory");                        \
      __builtin_amdgcn_s_barrier();                                                      \
    } else {                                                                             \
      asm volatile("s_waitcnt lgkmcnt(0)" ::: "memory");                                 \
    }                                                                                    \
    bf16x8_t aq[4][2];                                                                   \
    _Pragma("unroll") for (int st = 0; st < 4; ++st) {                                   \
      const int row = st * 16 + c16;                                                     \
      const int rsw = (row & 7) << 4;                                                    \
      _Pragma("unroll") for (int dt = 0; dt < 2; ++dt)                                   \
        aq[st][dt] =                                                                     \
            *(const bf16x8_t*)&qh[(row * 128 + ((dt * 64 + r16 * 16) ^ rsw)) >> 1];      \
    }                                                                                    \
    asm volatile("s_waitcnt lgkmcnt(0)" ::: "memory");                                   \
    __builtin_amdgcn_sched_barrier(0);                                                   \
    u16* sP = qh;                                                                        \
    _Pragma("unroll") for (int st = 0; st < 4; ++st) {                                   \
      f32x4_t accs[4];                                                                   \
      _Pragma("unroll") for (int nn = 0; nn < 4; ++nn) {                                 \
        const u16* kr = &kdw[(nn * 16 + c16) * 64];                                      \
        bf16x8_t b0 = *(const bf16x8_t*)&kr[((r16 * 16) ^ swz) >> 1];                    \
        bf16x8_t b1 = *(const bf16x8_t*)&kr[((64 + r16 * 16) ^ swz) >> 1];               \
        f32x4_t a = {0.f, 0.f, 0.f, 0.f};                                                \
        a = MFMA_BF16(aq[st][0], b0, a, 0, 0, 0);                                        \
        a = MFMA_BF16(aq[st][1], b1, a, 0, 0, 0);                                        \
        accs[nn] = a;                                                                    \
      }                                                                                  \
      float ex[4][4], rs[4];                                                             \
      _Pragma("unroll") for (int i = 0; i < 4; ++i) {                                    \
        float mx = fmaxf(fmaxf(accs[0][i], accs[1][i]), fmaxf(accs[2][i], accs[3][i]));  \
        _Pragma("unroll") for (int off = 1; off < 16; off <<= 1)                         \
          mx = fmaxf(mx, __shfl_xor(mx, off));                                           \
        mx *= 0.125f;                                                                    \
        float s = 0.f;                                                                   \
        _Pragma("unroll") for (int nn = 0; nn < 4; ++nn) {                               \
          float e = __expf(accs[nn][i] * 0.125f - mx);                                   \
          ex[nn][i] = e;                                                                 \
          s += e;                                                                        \
        }                                                                                \
        _Pragma("unroll") for (int off = 1; off < 16; off <<= 1)                         \
          s += __shfl_xor(s, off);                                                       \
        rs[i] = 1.f / s;                                                                 \
      }                                                                                  \
      _Pragma("unroll") for (int i = 0; i < 4; ++i) {                                    \
        const int row = r16 * 4 + i;                                                     \
        const int rsw = (row & 7) << 4;                                                  \
        _Pragma("unroll") for (int nn = 0; nn < 4; ++nn)                                 \
          sP[row * 64 + (((nn * 32 + c16 * 2) ^ rsw) >> 1)] = f2bf(ex[nn][i]);           \
      }                                                                                  \
      asm volatile("s_waitcnt lgkmcnt(0)" ::: "memory");                                 \
      bf16x8_t pa0 = *(const bf16x8_t*)&sP[c16 * 64 + (((r16 * 16) ^ swz) >> 1)];        \
      bf16x8_t pa1 = *(const bf16x8_t*)&sP[c16 * 64 + (((64 + r16 * 16) ^ swz) >> 1)];   \
      f32x4_t accv[4];                                                                   \
      _Pragma("unroll") for (int dt = 0; dt < 4; ++dt) {                                 \
        const u16* vr = &vdw[(dt * 16 + c16) * 64];                                      \
        bf16x8_t v0 = *(const bf16x8_t*)&vr[((r16 * 16) ^ swz) >> 1];                    \
        bf16x8_t v1 = *(const bf16x8_t*)&vr[((64 + r16 * 16) ^ swz) >> 1];               \
        f32x4_t a = {0.f, 0.f, 0.f, 0.f};                                                \
        a = MFMA_BF16(pa0, v0, a, 0, 0, 0);                                              \
        a = MFMA_BF16(pa1, v1, a, 0, 0, 0);                                              \
        accv[dt] = a;                                                                    \
      }                                                                                  \
      _Pragma("unroll") for (int i = 0; i < 4; ++i) {                                    \
        const int row = r16 * 4 + i;                                                     \
        const int rsw = (row & 7) << 4;                                                  \
        _Pragma("unroll") for (int dt = 0; dt < 4; ++dt)                                 \
          sP[row * 64 + (((dt * 32 + c16 * 2) ^ rsw) >> 1)] = f2bf(accv[dt][i] * rs[i]); \
      }                                                                                  \
      asm volatile("s_waitcnt lgkmcnt(0)" ::: "memory");                                 \
      const int srow_base = b * 4096 + s0b + wm * 128 + HALF * 64 + st * 16;             \
      _Pragma("unroll") for (int r = 0; r < 2; ++r) {                                    \
        const int row = r * 8 + (lane >> 3);                                             \
        const int cb = ((lane & 7) * 16) ^ ((row & 7) << 4);                             \
        bf16x8_t vv = *(const bf16x8_t*)&sP[row * 64 + (cb >> 1)];                       \
        *(bf16x8_t*)(av + (size_t)(srow_base + row) * 1024 + n_head * 64 +               \
                     (lane & 7) * 8) = vv;                                               \
      }                                                                                  \
    }                                                                                    \
  }

// ---------------- 256x256 8-phase q-GEMM with FUSED pooled attention ----------------
__global__ __launch_bounds__(512) void gemm256_attn(const u16* __restrict__ A,
                                                    const u16* __restrict__ BT,
                                                    const float* __restrict__ bias,
                                                    const u16* __restrict__ kdb,
                                                    const u16* __restrict__ vdTb,
                                                    u16* __restrict__ av) {
  __shared__ u16 sAB[65536];
  char* lds = (char*)sAB;
  const int t = threadIdx.x;
  const int lane = t & 63;
  const int w = t >> 6;
  const int wm = w >> 2, wn = w & 3;
  const int c16 = lane & 15, r16 = lane >> 4, c7 = c16 & 7;
  const int tile = (blockIdx.x & 7) * 32 + (blockIdx.x >> 3);
  const int bx = tile >> 2, by = tile & 3;
  f32x4_t acc[8][4] = {};
  bf16x8_t bfr[4][2];
  GEMM256_KLOOP(A, BT)

  // ---- fused attention epilogue ----
  asm volatile("s_waitcnt vmcnt(0)" ::: "memory");  // drain clamped dead stages
  __builtin_amdgcn_s_barrier();                     // LDS free for reuse

  const int b = bx >> 4;
  const int s0b = (bx & 15) * 256;
  char* kdL = lds + 65536;          // 32KB: 4 heads x [64k][64d] (swizzled)
  char* vdL = lds + 65536 + 32768;  // 32KB: 4 heads x [64d][64k] (swizzled)
  {
    const int kk = t >> 3;
    const int colb = ((t & 7) ^ (kk & 7)) << 4;
#pragma unroll
    for (int h = 0; h < 4; ++h) {
      const int n = by * 4 + h;
      async_load16((const char*)kdb + (size_t)(b * 64 + kk) * 2048 + n * 128 + colb,
                   kdL + h * 8192 + (t >> 6) * 1024);
      async_load16((const char*)vdTb + (size_t)(n * 64 + kk) * 512 + b * 128 + colb,
                   vdL + h * 8192 + (t >> 6) * 1024);
    }
  }
  u16* qh = (u16*)(lds + w * 8192);  // per-wave 8KB q half-tile region
  const int n_head = by * 4 + wn;
  const u16* kdw = (const u16*)(kdL + wn * 8192);
  const u16* vdw = (const u16*)(vdL + wn * 8192);
  const int swz = (c16 & 7) << 4;

  ATTN_EPI_HALF(0)
  ATTN_EPI_HALF(1)
}

extern "C" void kernel_launch(void* const* d_in, const int* in_sizes, int n_in,
                              void* d_out, int out_size, void* d_ws, size_t ws_size,
                              hipStream_t stream) {
  (void)in_sizes; (void)n_in; (void)out_size; (void)ws_size;
  const float* query = (const float*)d_in[0];
  const float* key   = (const float*)d_in[1];
  const float* value = (const float*)d_in[2];
  const float* Wq = (const float*)d_in[3];
  const float* bq = (const float*)d_in[4];
  const float* Wk = (const float*)d_in[5];
  const float* bk = (const float*)d_in[6];
  const float* Wv = (const float*)d_in[7];
  const float* bv = (const float*)d_in[8];
  const float* Wo = (const float*)d_in[9];
  const float* bo = (const float*)d_in[10];
  float* out = (float*)d_out;

  char* ws = (char*)d_ws;
  const size_t MB = 1024 * 1024;
  u16* WqT    = (u16*)(ws + 0 * MB);
  u16* WkT    = (u16*)(ws + 2 * MB);
  u16* WvT    = (u16*)(ws + 4 * MB);
  u16* WoT    = (u16*)(ws + 6 * MB);
  u16* keyd   = (u16*)(ws + 8 * MB);
  u16* valued = (u16*)(ws + 8 * MB + 512 * 1024);
  u16* kdb    = (u16*)(ws + 9 * MB);
  u16* vdTb   = (u16*)(ws + 9 * MB + 512 * 1024);
  u16* avb    = (u16*)(ws + 10 * MB);             // 32MB bf16 [16384][1024]
  u16* qcvt   = (u16*)((char*)d_out + 32 * MB);   // hi 32MB of d_out (final out overwrites)

  // single fused streaming pre-pass: downsample + query-cvt + weight transposes
  fused_stream<<<5632, 512, 0, stream>>>(query, key, value, Wq, Wk, Wv, Wo,
                                         qcvt, keyd, valued, WqT, WkT, WvT, WoT);

  gemm_kv<<<dim3(2, 8, 2), 256, 0, stream>>>(keyd, valued, WkT, WvT, bk, bv, kdb, vdTb);

  gemm256_attn<<<256, 512, 0, stream>>>(qcvt, WqT, bq, kdb, vdTb, avb);
  gemm256<false><<<256, 512, 0, stream>>>(avb, WoT, bo, out);
}

// Round 15
// 157.234 us; speedup vs baseline: 1.1152x; 1.0340x over previous
//
#include <hip/hip_runtime.h>

typedef unsigned short u16;
typedef unsigned int u32;
typedef __attribute__((ext_vector_type(8))) short bf16x8_t;
typedef __attribute__((ext_vector_type(4))) float f32x4_t;

// Problem constants: B=4, S=4096, H=1024, N=16, D=64, K-pool=64

#define MFMA_BF16 __builtin_amdgcn_mfma_f32_16x16x32_bf16

__device__ __forceinline__ u16 f2bf(float f) {
  union { float f; u32 u; } a; a.f = f;
  u32 u = a.u;
  u32 r = (u + 0x7FFFu + ((u >> 16) & 1u)) >> 16;  // RNE
  return (u16)r;
}

__device__ __forceinline__ void async_load16(const void* g, void* l) {
  __builtin_amdgcn_global_load_lds(
      (const __attribute__((address_space(1))) void*)g,
      (__attribute__((address_space(3))) void*)l, 16, 0, 0);
}

// stage 64 rows x 128B (8KB, one issue/thread) with chunk pre-swizzle
__device__ __forceinline__ void stage64(const u16* __restrict__ src,
                                        char* lds_base, int t) {
  const int r = t >> 3;
  const int gch = (t & 7) ^ (r & 7);
  async_load16(src + (size_t)r * 1024 + gch * 8, lds_base + (t >> 6) * 1024);
}

// ---------------- fused streaming pre-pass: downsample + query-cvt + 4x transpose ----------------
// z in [0,512): downsample key/value bucket; z in [512,4608): query fp32->bf16 chunk;
// z in [4608,5632): weight transpose tile. Streaming reads use nontemporal hints
// (touched exactly once). Stores remain cached (outputs re-read by later kernels;
// R13 A/B showed nt stores on the fp32 out regressed).
__global__ __launch_bounds__(512) void fused_stream(
    const float* __restrict__ query, const float* __restrict__ key,
    const float* __restrict__ value, const float* __restrict__ W0,
    const float* __restrict__ W1, const float* __restrict__ W2,
    const float* __restrict__ W3, u16* __restrict__ qcvt, u16* __restrict__ keyd,
    u16* __restrict__ valued, u16* __restrict__ T0, u16* __restrict__ T1,
    u16* __restrict__ T2, u16* __restrict__ T3) {
  __shared__ char smem[32768];
  const int z = blockIdx.x;
  const int t = threadIdx.x;
  if (z < 512) {
    // ---- downsample: contiguous 256KB region, wave-per-8-rows, deep-batched nt loads ----
    f32x4_t (*part)[256] = (f32x4_t(*)[256])smem;  // [8][256] f32x4 = 32KB
    const int bkk = z & 255;
    const float* x = (z >= 256) ? value : key;
    u16* xd = (z >= 256) ? valued : keyd;
    const int lane = t & 63, w = t >> 6;
    const float* base = x + (size_t)bkk * 65536 + (size_t)w * 8 * 1024;
#define LD4(j, s) \
  __builtin_nontemporal_load((const f32x4_t*)(base + (size_t)(j) * 1024 + ((s) * 64 + lane) * 4))
    f32x4_t a0 = {0.f, 0.f, 0.f, 0.f}, a1 = a0, a2 = a0, a3 = a0;
    f32x4_t u0 = LD4(0, 0), u1 = LD4(0, 1), u2 = LD4(0, 2), u3 = LD4(0, 3);
    f32x4_t u4 = LD4(1, 0), u5 = LD4(1, 1), u6 = LD4(1, 2), u7 = LD4(1, 3);
    f32x4_t v0 = LD4(2, 0), v1 = LD4(2, 1), v2 = LD4(2, 2), v3 = LD4(2, 3);
    f32x4_t v4 = LD4(3, 0), v5 = LD4(3, 1), v6 = LD4(3, 2), v7 = LD4(3, 3);
    a0 += u0; a1 += u1; a2 += u2; a3 += u3;
    a0 += u4; a1 += u5; a2 += u6; a3 += u7;
    u0 = LD4(4, 0); u1 = LD4(4, 1); u2 = LD4(4, 2); u3 = LD4(4, 3);
    u4 = LD4(5, 0); u5 = LD4(5, 1); u6 = LD4(5, 2); u7 = LD4(5, 3);
    a0 += v0; a1 += v1; a2 += v2; a3 += v3;
    a0 += v4; a1 += v5; a2 += v6; a3 += v7;
    v0 = LD4(6, 0); v1 = LD4(6, 1); v2 = LD4(6, 2); v3 = LD4(6, 3);
    v4 = LD4(7, 0); v5 = LD4(7, 1); v6 = LD4(7, 2); v7 = LD4(7, 3);
    a0 += u0; a1 += u1; a2 += u2; a3 += u3;
    a0 += u4; a1 += u5; a2 += u6; a3 += u7;
    a0 += v0; a1 += v1; a2 += v2; a3 += v3;
    a0 += v4; a1 += v5; a2 += v6; a3 += v7;
#undef LD4
    part[w][0 * 64 + lane] = a0;
    part[w][1 * 64 + lane] = a1;
    part[w][2 * 64 + lane] = a2;
    part[w][3 * 64 + lane] = a3;
    __syncthreads();
    if (t < 256) {
      f32x4_t s = {0.f, 0.f, 0.f, 0.f};
#pragma unroll
      for (int w2 = 0; w2 < 8; ++w2) s += part[w2][t];
      ushort4 r;
      r.x = f2bf(s[0] * 0.015625f);
      r.y = f2bf(s[1] * 0.015625f);
      r.z = f2bf(s[2] * 0.015625f);
      r.w = f2bf(s[3] * 0.015625f);
      *(ushort4*)(xd + (size_t)bkk * 1024 + t * 4) = r;  // cached: re-read by gemm_kv
    }
  } else if (z < 4608) {
    // ---- query fp32 -> bf16, 4096 elems per block (nt read; cached write) ----
    const size_t i = ((size_t)(z - 512) * 512 + t) * 8;
    const f32x4_t a = __builtin_nontemporal_load((const f32x4_t*)(query + i));
    const f32x4_t b = __builtin_nontemporal_load((const f32x4_t*)(query + i + 4));
    bf16x8_t o;
    o[0] = (short)f2bf(a[0]); o[1] = (short)f2bf(a[1]);
    o[2] = (short)f2bf(a[2]); o[3] = (short)f2bf(a[3]);
    o[4] = (short)f2bf(b[0]); o[5] = (short)f2bf(b[1]);
    o[6] = (short)f2bf(b[2]); o[7] = (short)f2bf(b[3]);
    *(bf16x8_t*)(qcvt + i) = o;
  } else {
    // ---- weight transpose 64x64 tile (nt fp32 read -> bf16 transposed, cached write) ----
    float (*tile)[65] = (float(*)[65])smem;  // [64][65]
    const int blk = z - 4608;
    const int wsel = blk >> 8, tidx = blk & 255;
    const float* W = (wsel == 0) ? W0 : (wsel == 1) ? W1 : (wsel == 2) ? W2 : W3;
    u16* WT = (wsel == 0) ? T0 : (wsel == 1) ? T1 : (wsel == 2) ? T2 : T3;
    const int tr = (tidx >> 4) * 64;
    const int tc = (tidx & 15) * 64;
#pragma unroll
    for (int i = 0; i < 8; ++i) {
      int idx = i * 512 + t;
      int r = idx >> 6, c = idx & 63;
      tile[r][c] = __builtin_nontemporal_load(W + (size_t)(tr + r) * 1024 + tc + c);
    }
    __syncthreads();
#pragma unroll
    for (int i = 0; i < 8; ++i) {
      int idx = i * 512 + t;
      int r = idx >> 6, c = idx & 63;
      WT[(size_t)(tc + r) * 1024 + tr + c] = f2bf(tile[c][r]);
    }
  }
}

// ---------------- fused small GEMMs (M=256): kd and vd^T in one launch ----------------
__global__ __launch_bounds__(256) void gemm_kv(const u16* __restrict__ A0,
                                               const u16* __restrict__ A1,
                                               const u16* __restrict__ BT0,
                                               const u16* __restrict__ BT1,
                                               const float* __restrict__ bias0,
                                               const float* __restrict__ bias1,
                                               u16* __restrict__ C0,
                                               u16* __restrict__ C1) {
  constexpr int K = 1024, BK = 32;
  __shared__ u16 sA[128 * BK];
  __shared__ u16 sB[128 * BK];
  const int z = blockIdx.z;
  const u16* A = z ? A1 : A0;
  const u16* BT = z ? BT1 : BT0;
  const float* bias = z ? bias1 : bias0;
  u16* Cv = z ? C1 : C0;
  const int t = threadIdx.x;
  const int lane = t & 63;
  const int w = t >> 6;
  const int wr = w >> 1, wc = w & 1;
  const int m0 = blockIdx.x * 128;
  const int n0 = blockIdx.y * 128;
  const int c16 = lane & 15, r16 = lane >> 4;

  f32x4_t acc[4][4] = {};

  for (int k0 = 0; k0 < K; k0 += BK) {
#pragma unroll
    for (int i = 0; i < 2; ++i) {
      const int idx = i * 256 + t;
      const int row = idx >> 2, ch = idx & 3;
      const int gch = ch ^ ((row >> 1) & 3);
      async_load16(A + (size_t)(m0 + row) * K + k0 + gch * 8,
                   (char*)sA + (i * 256 + w * 64) * 16);
    }
#pragma unroll
    for (int i = 0; i < 2; ++i) {
      const int idx = i * 256 + t;
      const int row = idx >> 2, ch = idx & 3;
      const int gch = ch ^ ((row >> 1) & 3);
      async_load16(BT + (size_t)(n0 + row) * K + k0 + gch * 8,
                   (char*)sB + (i * 256 + w * 64) * 16);
    }
    __syncthreads();

    bf16x8_t af[4], bfv[4];
#pragma unroll
    for (int m = 0; m < 4; ++m) {
      const int ra = wr * 64 + m * 16 + c16;
      af[m] = *(const bf16x8_t*)&sA[ra * BK + ((r16 ^ ((ra >> 1) & 3)) << 3)];
    }
#pragma unroll
    for (int n = 0; n < 4; ++n) {
      const int rb = wc * 64 + n * 16 + c16;
      bfv[n] = *(const bf16x8_t*)&sB[rb * BK + ((r16 ^ ((rb >> 1) & 3)) << 3)];
    }
#pragma unroll
    for (int m = 0; m < 4; ++m)
#pragma unroll
      for (int n = 0; n < 4; ++n)
        acc[m][n] = MFMA_BF16(af[m], bfv[n], acc[m][n], 0, 0, 0);
    __syncthreads();
  }

#pragma unroll
  for (int m = 0; m < 4; ++m) {
    const int row0 = m0 + wr * 64 + m * 16 + r16 * 4;
#pragma unroll
    for (int n = 0; n < 4; ++n) {
      const int col = n0 + wc * 64 + n * 16 + c16;
      const float bvl = bias[col];
#pragma unroll
      for (int i = 0; i < 4; ++i) {
        const float val = acc[m][n][i] + bvl;
        if (z)
          Cv[(size_t)col * 256 + row0 + i] = f2bf(val);   // vd^T layout [1024][256]
        else
          Cv[(size_t)(row0 + i) * 1024 + col] = f2bf(val);
      }
    }
  }
}

// ======== K-loop macro shared by gemm256 and gemm256_attn (identical schedule) ========
#define GEMM256_KLOOP(A_, BT_)                                                          \
  const u16* Ab = (A_) + (size_t)bx * 256 * 1024;                                       \
  const u16* Bb = (BT_) + (size_t)by * 256 * 1024;                                      \
  stage64(Ab,                   lds,                 t);                                \
  stage64(Ab + 128 * 1024,      lds + 128 * 128,     t);                                \
  stage64(Bb,                   lds + 32768,         t);                                \
  stage64(Bb + 64 * 1024,       lds + 32768 + 8192,  t);                                \
  stage64(Bb + 128 * 1024,      lds + 32768 + 16384, t);                                \
  stage64(Bb + 192 * 1024,      lds + 32768 + 24576, t);                                \
  stage64(Ab + 64 * 1024,       lds + 64 * 128,      t);                                \
  stage64(Ab + 192 * 1024,      lds + 192 * 128,     t);                                \
  stage64(Ab + 64,              lds + 65536,         t);                                \
  stage64(Ab + 128 * 1024 + 64, lds + 65536 + 16384, t);                                \
  stage64(Bb + 64,              lds + 98304,         t);                                \
  stage64(Bb + 64 * 1024 + 64,  lds + 98304 + 8192,  t);                                \
  stage64(Bb + 128 * 1024 + 64, lds + 98304 + 16384, t);                                \
  stage64(Bb + 192 * 1024 + 64, lds + 98304 + 24576, t);                                \
  asm volatile("s_waitcnt vmcnt(6)" ::: "memory");                                      \
  __builtin_amdgcn_s_barrier();                                                         \
  for (int kt = 0; kt < 16; ++kt) {                                                     \
    const int slot = kt & 1;                                                            \
    const u16* sAs = (const u16*)(lds + slot * 65536);                                  \
    const u16* sBs = (const u16*)(lds + slot * 65536 + 32768);                          \
    char* sAn = lds + (slot ^ 1) * 65536;                                               \
    char* sAc = lds + slot * 65536;                                                     \
    char* sBc = lds + slot * 65536 + 32768;                                             \
    const int k1 = (kt < 15 ? kt + 1 : 15) * 64;                                        \
    const int k2 = (kt < 14 ? kt + 2 : 15) * 64;                                        \
    bf16x8_t af[4][2];                                                                  \
    _Pragma("unroll") for (int m = 0; m < 4; ++m) {                                     \
      const int row = wm * 128 + m * 16 + c16;                                          \
      _Pragma("unroll") for (int kk = 0; kk < 2; ++kk)                                  \
        af[m][kk] = *(const bf16x8_t*)&sAs[row * 64 + (((kk * 4 + r16) ^ c7) << 3)];    \
    }                                                                                   \
    _Pragma("unroll") for (int n = 0; n < 2; ++n) {                                     \
      const int row = wn * 64 + n * 16 + c16;                                           \
      _Pragma("unroll") for (int kk = 0; kk < 2; ++kk)                                  \
        bfr[n][kk] = *(const bf16x8_t*)&sBs[row * 64 + (((kk * 4 + r16) ^ c7) << 3)];   \
    }                                                                                   \
    stage64(Ab + (size_t)64 * 1024 + k1,  sAn + 64 * 128,  t);                          \
    stage64(Ab + (size_t)192 * 1024 + k1, sAn + 192 * 128, t);                          \
    asm volatile("" ::: "memory");                                                      \
    __builtin_amdgcn_s_barrier();                                                       \
    asm volatile("s_waitcnt lgkmcnt(0)" ::: "memory");                                  \
    __builtin_amdgcn_sched_barrier(0);                                                  \
    __builtin_amdgcn_s_setprio(1);                                                      \
    _Pragma("unroll") for (int m = 0; m < 4; ++m)                                       \
      _Pragma("unroll") for (int n = 0; n < 2; ++n)                                     \
        _Pragma("unroll") for (int kk = 0; kk < 2; ++kk)                                \
          acc[m][n] = MFMA_BF16(af[m][kk], bfr[n][kk], acc[m][n], 0, 0, 0);             \
    __builtin_amdgcn_s_setprio(0);                                                      \
    asm volatile("" ::: "memory");                                                      \
    __builtin_amdgcn_s_barrier();                                                       \
    _Pragma("unroll") for (int n = 2; n < 4; ++n) {                                     \
      const int row = wn * 64 + n * 16 + c16;                                           \
      _Pragma("unroll") for (int kk = 0; kk < 2; ++kk)                                  \
        bfr[n][kk] = *(const bf16x8_t*)&sBs[row * 64 + (((kk * 4 + r16) ^ c7) << 3)];   \
    }                                                                                   \
    stage64(Ab + k2,                      sAc,             t);                          \
    stage64(Ab + (size_t)128 * 1024 + k2, sAc + 128 * 128, t);                          \
    asm volatile("" ::: "memory");                                                      \
    __builtin_amdgcn_s_barrier();                                                       \
    asm volatile("s_waitcnt lgkmcnt(0)" ::: "memory");                                  \
    __builtin_amdgcn_sched_barrier(0);                                                  \
    __builtin_amdgcn_s_setprio(1);                                                      \
    _Pragma("unroll") for (int m = 0; m < 4; ++m)                                       \
      _Pragma("unroll") for (int n = 2; n < 4; ++n)                                     \
        _Pragma("unroll") for (int kk = 0; kk < 2; ++kk)                                \
          acc[m][n] = MFMA_BF16(af[m][kk], bfr[n][kk], acc[m][n], 0, 0, 0);             \
    __builtin_amdgcn_s_setprio(0);                                                      \
    asm volatile("s_waitcnt vmcnt(10)" ::: "memory");                                   \
    __builtin_amdgcn_s_barrier();                                                       \
    _Pragma("unroll") for (int m = 0; m < 4; ++m) {                                     \
      const int row = wm * 128 + 64 + m * 16 + c16;                                     \
      _Pragma("unroll") for (int kk = 0; kk < 2; ++kk)                                  \
        af[m][kk] = *(const bf16x8_t*)&sAs[row * 64 + (((kk * 4 + r16) ^ c7) << 3)];    \
    }                                                                                   \
    stage64(Bb + k2,                     sBc,        t);                                \
    stage64(Bb + (size_t)64 * 1024 + k2, sBc + 8192, t);                                \
    asm volatile("" ::: "memory");                                                      \
    __builtin_amdgcn_s_barrier();                                                       \
    asm volatile("s_waitcnt lgkmcnt(0)" ::: "memory");                                  \
    __builtin_amdgcn_sched_barrier(0);                                                  \
    __builtin_amdgcn_s_setprio(1);                                                      \
    _Pragma("unroll") for (int m = 0; m < 4; ++m)                                       \
      _Pragma("unroll") for (int n = 0; n < 2; ++n)                                     \
        _Pragma("unroll") for (int kk = 0; kk < 2; ++kk)                                \
          acc[4 + m][n] = MFMA_BF16(af[m][kk], bfr[n][kk], acc[4 + m][n], 0, 0, 0);     \
    __builtin_amdgcn_s_setprio(0);                                                      \
    asm volatile("" ::: "memory");                                                      \
    __builtin_amdgcn_s_barrier();                                                       \
    stage64(Bb + (size_t)128 * 1024 + k2, sBc + 16384, t);                              \
    stage64(Bb + (size_t)192 * 1024 + k2, sBc + 24576, t);                              \
    asm volatile("" ::: "memory");                                                      \
    __builtin_amdgcn_s_barrier();                                                       \
    __builtin_amdgcn_sched_barrier(0);                                                  \
    __builtin_amdgcn_s_setprio(1);                                                      \
    _Pragma("unroll") for (int m = 0; m < 4; ++m)                                       \
      _Pragma("unroll") for (int n = 2; n < 4; ++n)                                     \
        _Pragma("unroll") for (int kk = 0; kk < 2; ++kk)                                \
          acc[4 + m][n] = MFMA_BF16(af[m][kk], bfr[n][kk], acc[4 + m][n], 0, 0, 0);     \
    __builtin_amdgcn_s_setprio(0);                                                      \
    asm volatile("s_waitcnt vmcnt(8)" ::: "memory");                                    \
    __builtin_amdgcn_s_barrier();                                                       \
  }

// ---------------- 256x256 8-phase GEMM (plain epilogue; fp32 C cached stores) ----------------
template <bool C_BF16>
__global__ __launch_bounds__(512) void gemm256(const u16* __restrict__ A,
                                               const u16* __restrict__ BT,
                                               const float* __restrict__ bias,
                                               void* __restrict__ Cv) {
  __shared__ u16 sAB[65536];
  char* lds = (char*)sAB;
  const int t = threadIdx.x;
  const int lane = t & 63;
  const int w = t >> 6;
  const int wm = w >> 2, wn = w & 3;
  const int c16 = lane & 15, r16 = lane >> 4, c7 = c16 & 7;
  const int tile = (blockIdx.x & 7) * 32 + (blockIdx.x >> 3);
  const int bx = tile >> 2, by = tile & 3;
  f32x4_t acc[8][4] = {};
  bf16x8_t bfr[4][2];
  GEMM256_KLOOP(A, BT)
#pragma unroll
  for (int m = 0; m < 8; ++m) {
    const int grow = bx * 256 + wm * 128 + m * 16 + r16 * 4;
#pragma unroll
    for (int n = 0; n < 4; ++n) {
      const int col = by * 256 + wn * 64 + n * 16 + c16;
      const float bvl = bias[col];
#pragma unroll
      for (int i = 0; i < 4; ++i) {
        const float val = acc[m][n][i] + bvl;
        if constexpr (C_BF16)
          ((u16*)Cv)[(size_t)(grow + i) * 1024 + col] = f2bf(val);
        else
          ((float*)Cv)[(size_t)(grow + i) * 1024 + col] = val;
      }
    }
  }
}

// ======== fused attention epilogue half (HALF is a LITERAL 0/1 -> all static idx) ========
#define ATTN_EPI_HALF(HALF)                                                              \
  {                                                                                      \
    asm volatile("s_waitcnt lgkmcnt(0)" ::: "memory");                                   \
    _Pragma("unroll") for (int m = 0; m < 4; ++m)                                        \
      _Pragma("unroll") for (int nq = 0; nq < 4; ++nq) {                                 \
        const int d = nq * 16 + c16;                                                     \
        const float bvl = bias[n_head * 64 + d];                                         \
        _Pragma("unroll") for (int i = 0; i < 4; ++i) {                                  \
          const int row = m * 16 + r16 * 4 + i;                                          \
          qh[(row * 128 + ((d * 2) ^ ((row & 7) << 4))) >> 1] =                          \
              f2bf(acc[HALF * 4 + m][nq][i] + bvl);                                      \
        }                                                                                \
      }                                                                                  \
    if (HALF == 0) {                                                                     \
      asm volatile("s_waitcnt vmcnt(0) lgkmcnt(0)" ::: "memory");                        \
      __builtin_amdgcn_s_barrier();                                                      \
    } else {                                                                             \
      asm volatile("s_waitcnt lgkmcnt(0)" ::: "memory");                                 \
    }                                                                                    \
    bf16x8_t aq[4][2];                                                                   \
    _Pragma("unroll") for (int st = 0; st < 4; ++st) {                                   \
      const int row = st * 16 + c16;                                                     \
      const int rsw = (row & 7) << 4;                                                    \
      _Pragma("unroll") for (int dt = 0; dt < 2; ++dt)                                   \
        aq[st][dt] =                                                                     \
            *(const bf16x8_t*)&qh[(row * 128 + ((dt * 64 + r16 * 16) ^ rsw)) >> 1];      \
    }                                                                                    \
    asm volatile("s_waitcnt lgkmcnt(0)" ::: "memory");                                   \
    __builtin_amdgcn_sched_barrier(0);                                                   \
    u16* sP = qh;                                                                        \
    _Pragma("unroll") for (int st = 0; st < 4; ++st) {                                   \
      f32x4_t accs[4];                                                                   \
      _Pragma("unroll") for (int nn = 0; nn < 4; ++nn) {                                 \
        const u16* kr = &kdw[(nn * 16 + c16) * 64];                                      \
        bf16x8_t b0 = *(const bf16x8_t*)&kr[((r16 * 16) ^ swz) >> 1];                    \
        bf16x8_t b1 = *(const bf16x8_t*)&kr[((64 + r16 * 16) ^ swz) >> 1];               \
        f32x4_t a = {0.f, 0.f, 0.f, 0.f};                                                \
        a = MFMA_BF16(aq[st][0], b0, a, 0, 0, 0);                                        \
        a = MFMA_BF16(aq[st][1], b1, a, 0, 0, 0);                                        \
        accs[nn] = a;                                                                    \
      }                                                                                  \
      float ex[4][4], rs[4];                                                             \
      _Pragma("unroll") for (int i = 0; i < 4; ++i) {                                    \
        float mx = fmaxf(fmaxf(accs[0][i], accs[1][i]), fmaxf(accs[2][i], accs[3][i]));  \
        _Pragma("unroll") for (int off = 1; off < 16; off <<= 1)                         \
          mx = fmaxf(mx, __shfl_xor(mx, off));                                           \
        mx *= 0.125f;                                                                    \
        float s = 0.f;                                                                   \
        _Pragma("unroll") for (int nn = 0; nn < 4; ++nn) {                               \
          float e = __expf(accs[nn][i] * 0.125f - mx);                                   \
          ex[nn][i] = e;                                                                 \
          s += e;                                                                        \
        }                                                                                \
        _Pragma("unroll") for (int off = 1; off < 16; off <<= 1)                         \
          s += __shfl_xor(s, off);                                                       \
        rs[i] = 1.f / s;                                                                 \
      }                                                                                  \
      _Pragma("unroll") for (int i = 0; i < 4; ++i) {                                    \
        const int row = r16 * 4 + i;                                                     \
        const int rsw = (row & 7) << 4;                                                  \
        _Pragma("unroll") for (int nn = 0; nn < 4; ++nn)                                 \
          sP[row * 64 + (((nn * 32 + c16 * 2) ^ rsw) >> 1)] = f2bf(ex[nn][i]);           \
      }                                                                                  \
      asm volatile("s_waitcnt lgkmcnt(0)" ::: "memory");                                 \
      bf16x8_t pa0 = *(const bf16x8_t*)&sP[c16 * 64 + (((r16 * 16) ^ swz) >> 1)];        \
      bf16x8_t pa1 = *(const bf16x8_t*)&sP[c16 * 64 + (((64 + r16 * 16) ^ swz) >> 1)];   \
      f32x4_t accv[4];                                                                   \
      _Pragma("unroll") for (int dt = 0; dt < 4; ++dt) {                                 \
        const u16* vr = &vdw[(dt * 16 + c16) * 64];                                      \
        bf16x8_t v0 = *(const bf16x8_t*)&vr[((r16 * 16) ^ swz) >> 1];                    \
        bf16x8_t v1 = *(const bf16x8_t*)&vr[((64 + r16 * 16) ^ swz) >> 1];               \
        f32x4_t a = {0.f, 0.f, 0.f, 0.f};                                                \
        a = MFMA_BF16(pa0, v0, a, 0, 0, 0);                                              \
        a = MFMA_BF16(pa1, v1, a, 0, 0, 0);                                              \
        accv[dt] = a;                                                                    \
      }                                                                                  \
      _Pragma("unroll") for (int i = 0; i < 4; ++i) {                                    \
        const int row = r16 * 4 + i;                                                     \
        const int rsw = (row & 7) << 4;                                                  \
        _Pragma("unroll") for (int dt = 0; dt < 4; ++dt)                                 \
          sP[row * 64 + (((dt * 32 + c16 * 2) ^ rsw) >> 1)] = f2bf(accv[dt][i] * rs[i]); \
      }                                                                                  \
      asm volatile("s_waitcnt lgkmcnt(0)" ::: "memory");                                 \
      const int srow_base = b * 4096 + s0b + wm * 128 + HALF * 64 + st * 16;             \
      _Pragma("unroll") for (int r = 0; r < 2; ++r) {                                    \
        const int row = r * 8 + (lane >> 3);                                             \
        const int cb = ((lane & 7) * 16) ^ ((row & 7) << 4);                             \
        bf16x8_t vv = *(const bf16x8_t*)&sP[row * 64 + (cb >> 1)];                       \
        *(bf16x8_t*)(av + (size_t)(srow_base + row) * 1024 + n_head * 64 +               \
                     (lane & 7) * 8) = vv;                                               \
      }                                                                                  \
    }                                                                                    \
  }

// ---------------- 256x256 8-phase q-GEMM with FUSED pooled attention ----------------
__global__ __launch_bounds__(512) void gemm256_attn(const u16* __restrict__ A,
                                                    const u16* __restrict__ BT,
                                                    const float* __restrict__ bias,
                                                    const u16* __restrict__ kdb,
                                                    const u16* __restrict__ vdTb,
                                                    u16* __restrict__ av) {
  __shared__ u16 sAB[65536];
  char* lds = (char*)sAB;
  const int t = threadIdx.x;
  const int lane = t & 63;
  const int w = t >> 6;
  const int wm = w >> 2, wn = w & 3;
  const int c16 = lane & 15, r16 = lane >> 4, c7 = c16 & 7;
  const int tile = (blockIdx.x & 7) * 32 + (blockIdx.x >> 3);
  const int bx = tile >> 2, by = tile & 3;
  f32x4_t acc[8][4] = {};
  bf16x8_t bfr[4][2];
  GEMM256_KLOOP(A, BT)

  // ---- fused attention epilogue ----
  asm volatile("s_waitcnt vmcnt(0)" ::: "memory");  // drain clamped dead stages
  __builtin_amdgcn_s_barrier();                     // LDS free for reuse

  const int b = bx >> 4;
  const int s0b = (bx & 15) * 256;
  char* kdL = lds + 65536;          // 32KB: 4 heads x [64k][64d] (swizzled)
  char* vdL = lds + 65536 + 32768;  // 32KB: 4 heads x [64d][64k] (swizzled)
  {
    const int kk = t >> 3;
    const int colb = ((t & 7) ^ (kk & 7)) << 4;
#pragma unroll
    for (int h = 0; h < 4; ++h) {
      const int n = by * 4 + h;
      async_load16((const char*)kdb + (size_t)(b * 64 + kk) * 2048 + n * 128 + colb,
                   kdL + h * 8192 + (t >> 6) * 1024);
      async_load16((const char*)vdTb + (size_t)(n * 64 + kk) * 512 + b * 128 + colb,
                   vdL + h * 8192 + (t >> 6) * 1024);
    }
  }
  u16* qh = (u16*)(lds + w * 8192);  // per-wave 8KB q half-tile region
  const int n_head = by * 4 + wn;
  const u16* kdw = (const u16*)(kdL + wn * 8192);
  const u16* vdw = (const u16*)(vdL + wn * 8192);
  const int swz = (c16 & 7) << 4;

  ATTN_EPI_HALF(0)
  ATTN_EPI_HALF(1)
}

extern "C" void kernel_launch(void* const* d_in, const int* in_sizes, int n_in,
                              void* d_out, int out_size, void* d_ws, size_t ws_size,
                              hipStream_t stream) {
  (void)in_sizes; (void)n_in; (void)out_size; (void)ws_size;
  const float* query = (const float*)d_in[0];
  const float* key   = (const float*)d_in[1];
  const float* value = (const float*)d_in[2];
  const float* Wq = (const float*)d_in[3];
  const float* bq = (const float*)d_in[4];
  const float* Wk = (const float*)d_in[5];
  const float* bk = (const float*)d_in[6];
  const float* Wv = (const float*)d_in[7];
  const float* bv = (const float*)d_in[8];
  const float* Wo = (const float*)d_in[9];
  const float* bo = (const float*)d_in[10];
  float* out = (float*)d_out;

  char* ws = (char*)d_ws;
  const size_t MB = 1024 * 1024;
  u16* WqT    = (u16*)(ws + 0 * MB);
  u16* WkT    = (u16*)(ws + 2 * MB);
  u16* WvT    = (u16*)(ws + 4 * MB);
  u16* WoT    = (u16*)(ws + 6 * MB);
  u16* keyd   = (u16*)(ws + 8 * MB);
  u16* valued = (u16*)(ws + 8 * MB + 512 * 1024);
  u16* kdb    = (u16*)(ws + 9 * MB);
  u16* vdTb   = (u16*)(ws + 9 * MB + 512 * 1024);
  u16* avb    = (u16*)(ws + 10 * MB);             // 32MB bf16 [16384][1024]
  u16* qcvt   = (u16*)((char*)d_out + 32 * MB);   // hi 32MB of d_out (final out overwrites)

  // single fused streaming pre-pass: downsample + query-cvt + weight transposes
  fused_stream<<<5632, 512, 0, stream>>>(query, key, value, Wq, Wk, Wv, Wo,
                                         qcvt, keyd, valued, WqT, WkT, WvT, WoT);

  gemm_kv<<<dim3(2, 8, 2), 256, 0, stream>>>(keyd, valued, WkT, WvT, bk, bv, kdb, vdTb);

  gemm256_attn<<<256, 512, 0, stream>>>(qcvt, WqT, bq, kdb, vdTb, avb);
  gemm256<false><<<256, 512, 0, stream>>>(avb, WoT, bo, out);
}